// Round 9
// baseline (189.736 us; speedup 1.0000x reference)
//
#include <hip/hip_runtime.h>
#include <hip/hip_bf16.h>
#include <type_traits>

typedef __attribute__((ext_vector_type(8))) short bf16x8;
typedef __attribute__((ext_vector_type(4))) float f32x4;
typedef __attribute__((ext_vector_type(4))) int   i32x4;

static __device__ __forceinline__ void stage16(const void* g, void* l) {
  __builtin_amdgcn_global_load_lds((const __attribute__((address_space(1))) void*)g,
                                   (__attribute__((address_space(3))) void*)l,
                                   16, 0, 0);
}

// ---------------- prep ----------------
// y==0 (1024 blocks): x f32 -> int8. y==1/2 (96 blocks): maxabs(w1/w2).
__global__ void prep_kernel(const float4* __restrict__ x, uchar4* __restrict__ xq, int n4x,
                            const float4* __restrict__ w1, const float4* __restrict__ w2,
                            int n4w, unsigned* __restrict__ mx) {
  if (blockIdx.y == 0) {
    const int stride = gridDim.x * blockDim.x;
    for (int i = blockIdx.x * blockDim.x + threadIdx.x; i < n4x; i += stride) {
      float4 v = x[i];
      uchar4 o;
      o.x = (unsigned char)(char)fminf(fmaxf(v.x, -127.f), 127.f);
      o.y = (unsigned char)(char)fminf(fmaxf(v.y, -127.f), 127.f);
      o.z = (unsigned char)(char)fminf(fmaxf(v.z, -127.f), 127.f);
      o.w = (unsigned char)(char)fminf(fmaxf(v.w, -127.f), 127.f);
      xq[i] = o;
    }
  } else {
    if (blockIdx.x >= 96) return;
    __shared__ unsigned red[4];
    const float4* w = (blockIdx.y == 1) ? w1 : w2;
    unsigned m = 0;
    const int stride = 96 * 256;
    for (int i = blockIdx.x * blockDim.x + threadIdx.x; i < n4w; i += stride) {
      float4 v = w[i];
      unsigned a;
      a = __float_as_uint(fabsf(v.x)); m = m > a ? m : a;
      a = __float_as_uint(fabsf(v.y)); m = m > a ? m : a;
      a = __float_as_uint(fabsf(v.z)); m = m > a ? m : a;
      a = __float_as_uint(fabsf(v.w)); m = m > a ? m : a;
    }
#pragma unroll
    for (int off = 32; off > 0; off >>= 1) {
      unsigned t = (unsigned)__shfl_down((int)m, off, 64);
      m = m > t ? m : t;
    }
    if ((threadIdx.x & 63) == 0) red[threadIdx.x >> 6] = m;
    __syncthreads();
    if (threadIdx.x == 0) {
      unsigned t0 = red[0] > red[1] ? red[0] : red[1];
      unsigned t1 = red[2] > red[3] ? red[2] : red[3];
      atomicMax(mx + blockIdx.y - 1, t0 > t1 ? t0 : t1);
    }
  }
}

// y==0: w1 -> int8 ; y==1: w2 -> int8 (w_int exact in i8) ; y==2 blk0: biases+scale.
__global__ void quantwb_kernel(const float4* __restrict__ w1, const float4* __restrict__ w2,
                               uchar4* __restrict__ w1q, uchar4* __restrict__ w2q,
                               const float* __restrict__ b1, const float* __restrict__ b2,
                               float* __restrict__ b1i, float* __restrict__ b2i,
                               const unsigned* __restrict__ mx, const float* __restrict__ a_s,
                               float* __restrict__ s_out, int n4, int H, int D) {
  const float ws1 = __uint_as_float(mx[0]) / 127.0f;
  const float ws2 = __uint_as_float(mx[1]) / 127.0f;
  const int stride = gridDim.x * blockDim.x;
  if (blockIdx.y <= 1) {
    const float4* w = blockIdx.y ? w2 : w1;
    uchar4* wq = blockIdx.y ? w2q : w1q;
    const float ws = blockIdx.y ? ws2 : ws1;
    for (int i = blockIdx.x * blockDim.x + threadIdx.x; i < n4; i += stride) {
      float4 v = w[i];
      uchar4 o;
      o.x = (unsigned char)(char)fminf(fmaxf(rintf(v.x / ws), -127.f), 127.f);
      o.y = (unsigned char)(char)fminf(fmaxf(rintf(v.y / ws), -127.f), 127.f);
      o.z = (unsigned char)(char)fminf(fmaxf(rintf(v.z / ws), -127.f), 127.f);
      o.w = (unsigned char)(char)fminf(fmaxf(rintf(v.w / ws), -127.f), 127.f);
      wq[i] = o;
    }
  } else {
    if (blockIdx.x != 0) return;
    const float s0 = a_s[0];
    const float s1 = s0 * ws1;
    const float d1 = ws1 * s0;
    const float d2 = ws2 * s1;
    if (threadIdx.x == 0) s_out[0] = s1 * ws2;
    for (int i = threadIdx.x; i < H; i += blockDim.x) {
      float q = rintf(b1[i] / d1);
      b1i[i] = fminf(fmaxf(q, -2147483647.f), 2147483647.f);
    }
    for (int i = threadIdx.x; i < D; i += blockDim.x) {
      float q = rintf(b2[i] / d2);
      b2i[i] = fminf(fmaxf(q, -2147483647.f), 2147483647.f);
    }
  }
}

// ---------------- fc1: 256x256 int8 GEMM, 8 waves, 2-slot BK=128B ----------------
// Epilogue: h = acc + b1 (exact), per-row-chunk (256 cols) int8 quantization;
// writes h_q (i8) + stab[row][12] scale table (s = rowchunkmax/127).

__global__ __launch_bounds__(512, 2) void gemm_fc1(
    const char* __restrict__ A, const char* __restrict__ Bt,
    const float* __restrict__ b1f, unsigned char* __restrict__ hq,
    float* __restrict__ stab, int M, int N, int Kb)
{
  __shared__ char lds[2 * 65536];
  const int tid = threadIdx.x;
  const int lane = tid & 63;
  const int wave = tid >> 6;
  const int wr = wave >> 2;            // 0..1
  const int wc = wave & 3;             // 0..3

  // 16-row-tile bands, col-major within band (A-band stays L2-resident)
  const int nbx = M / 256;             // 49
  const int nby = N / 256;             // 12
  const int bandSize = 16 * nby;
  const int b = blockIdx.x / bandSize;
  const int local = blockIdx.x - b * bandSize;
  const int r0 = b * 16;
  const int rn = min(16, nbx - r0);
  const int c = local / rn;
  const int r = r0 + (local - c * rn);
  const int row0 = r * 256;
  const int col0 = c * 256;

  const int srow = tid >> 3;
  const int chunk = (tid & 7) ^ (srow & 7);
  const char* Ag = A + (size_t)(row0 + srow) * Kb + chunk * 16;
  const char* Bg = Bt + (size_t)(col0 + srow) * Kb + chunk * 16;
  const int wb = wave * 1024;

  auto stage = [&](int slot, int st) {
    char* da = lds + slot * 65536 + wb;
    char* db = lds + slot * 65536 + 32768 + wb;
    const int ko = st << 7;
#pragma unroll
    for (int i = 0; i < 4; ++i)
      stage16(Ag + ko + (size_t)(i * 64) * Kb, da + i * 8192);
#pragma unroll
    for (int i = 0; i < 4; ++i)
      stage16(Bg + ko + (size_t)(i * 64) * Kb, db + i * 8192);
  };

  i32x4 acc[8][4];
#pragma unroll
  for (int i = 0; i < 8; ++i)
#pragma unroll
    for (int j = 0; j < 4; ++j) acc[i][j] = (i32x4)(0);

  const int nS = Kb >> 7;              // 6
  stage(0, 0);
  stage(1, 1);
  asm volatile("s_waitcnt vmcnt(8)" ::: "memory");
  __builtin_amdgcn_s_barrier();

  const int fr = lane & 15;
  const int fg = lane >> 4;
  const int ch0 = ((fg ^ (fr & 7)) & 7) << 4;
  const int Abase = (wr * 128 + fr) * 128;
  const int Bbase = 32768 + (wc * 64 + fr) * 128;

  for (int t = 0; t < nS; ++t) {
    const int so = (t & 1) << 16;
    i32x4 af[8], bf[4];
#pragma unroll
    for (int mf = 0; mf < 8; ++mf) af[mf] = *(const i32x4*)(lds + so + Abase + mf * 2048 + ch0);
#pragma unroll
    for (int nf = 0; nf < 4; ++nf) bf[nf] = *(const i32x4*)(lds + so + Bbase + nf * 2048 + ch0);
    __builtin_amdgcn_s_setprio(1);
#pragma unroll
    for (int mf = 0; mf < 8; ++mf)
#pragma unroll
      for (int nf = 0; nf < 4; ++nf)
        acc[mf][nf] = __builtin_amdgcn_mfma_i32_16x16x64_i8(af[mf], bf[nf], acc[mf][nf], 0, 0, 0);
    __builtin_amdgcn_s_setprio(0);
#pragma unroll
    for (int mf = 0; mf < 8; ++mf) af[mf] = *(const i32x4*)(lds + so + Abase + mf * 2048 + (ch0 ^ 64));
#pragma unroll
    for (int nf = 0; nf < 4; ++nf) bf[nf] = *(const i32x4*)(lds + so + Bbase + nf * 2048 + (ch0 ^ 64));
    asm volatile("s_waitcnt lgkmcnt(0)" ::: "memory");
    __builtin_amdgcn_sched_barrier(0);
    __builtin_amdgcn_s_barrier();
    const bool st = (t + 2 < nS);
    if (st) stage(t & 1, t + 2);
    __builtin_amdgcn_s_setprio(1);
#pragma unroll
    for (int mf = 0; mf < 8; ++mf)
#pragma unroll
      for (int nf = 0; nf < 4; ++nf)
        acc[mf][nf] = __builtin_amdgcn_mfma_i32_16x16x64_i8(af[mf], bf[nf], acc[mf][nf], 0, 0, 0);
    __builtin_amdgcn_s_setprio(0);
    if (t + 1 < nS) {
      if (st) asm volatile("s_waitcnt vmcnt(8)" ::: "memory");
      else    asm volatile("s_waitcnt vmcnt(0)" ::: "memory");
      __builtin_amdgcn_s_barrier();
    }
  }

  // ---- epilogue: per-row-chunk int8 quantization ----
  __syncthreads();                     // safe LDS reuse
  float* rowtab = (float*)lds;         // [256][4]
  const int orow_l = wr * 128 + fg * 4;
  const int ocol = col0 + wc * 64 + fr;
  float bv[4];
#pragma unroll
  for (int nf = 0; nf < 4; ++nf) bv[nf] = b1f[ocol + nf * 16];

#pragma unroll
  for (int mf = 0; mf < 8; ++mf) {
    float rmax[4] = {0.f, 0.f, 0.f, 0.f};
#pragma unroll
    for (int nf = 0; nf < 4; ++nf)
#pragma unroll
      for (int rg = 0; rg < 4; ++rg) {
        float v = (float)acc[mf][nf][rg] + bv[nf];
        rmax[rg] = fmaxf(rmax[rg], fabsf(v));
      }
#pragma unroll
    for (int rg = 0; rg < 4; ++rg) {
#pragma unroll
      for (int m = 1; m <= 8; m <<= 1)
        rmax[rg] = fmaxf(rmax[rg], __shfl_xor(rmax[rg], m, 64));
      if (fr == 0) rowtab[(orow_l + mf * 16 + rg) * 4 + wc] = rmax[rg];
    }
  }
  __syncthreads();
#pragma unroll
  for (int mf = 0; mf < 8; ++mf) {
#pragma unroll
    for (int rg = 0; rg < 4; ++rg) {
      const int lr = orow_l + mf * 16 + rg;
      float4 rt = *(const float4*)&rowtab[lr * 4];
      float rm = fmaxf(fmaxf(rt.x, rt.y), fmaxf(rt.z, rt.w));
      float inv = rm > 0.f ? 127.f / rm : 0.f;
      if (wc == 0 && fr == 0) stab[(size_t)(row0 + lr) * 12 + c] = rm * (1.f / 127.f);
#pragma unroll
      for (int nf = 0; nf < 4; ++nf) {
        float v = (float)acc[mf][nf][rg] + bv[nf];
        hq[(size_t)(row0 + lr) * N + ocol + nf * 16] =
            (unsigned char)(signed char)(int)rintf(v * inv);
      }
    }
  }
}

// ---------------- fc2: 128x128 int8 GEMM with per-chunk rescale ----------------
// A = h_q (i8, per-row-chunk scales in stab), B = w2_int (i8, exact).
// int32 accum per 256-k chunk (2 steps) -> acc_f += s_row * (float)acc_i.
// Scales staged once into LDS (6KB past the 64KB slots): in-loop scale reads
// use lgkm only -> counted vmcnt(8) bookkeeping stays exact.

__global__ __launch_bounds__(256) void gemm_fc2(
    const char* __restrict__ A, const char* __restrict__ Bt,
    const float* __restrict__ bias, const float* __restrict__ stab,
    float* __restrict__ Cout, int M, int N, int Kb)
{
  __shared__ char lds[2 * 32768 + 6144];
  const int tid = threadIdx.x;
  const int lane = tid & 63;
  const int wave = tid >> 6;
  const int wr = wave >> 1;
  const int wc = wave & 1;

  const int nbx = M / 128;
  const int nby = N / 128;
  const int nwg = nbx * nby;
  const int q8 = nwg >> 3, r8 = nwg & 7;
  const int xcd = blockIdx.x & 7, bidx = blockIdx.x >> 3;
  const int wg = (xcd < r8 ? xcd * (q8 + 1) : r8 * (q8 + 1) + (xcd - r8) * q8) + bidx;
  const int r = wg / nby;
  const int c = wg % nby;
  const int row0 = r * 128;
  const int col0 = c * 128;

  const int srow = tid >> 3;
  const int chunk = (tid & 7) ^ (srow & 7);
  const char* Ag = A + (size_t)(row0 + srow) * Kb + chunk * 16;
  const char* Bg = Bt + (size_t)(col0 + srow) * Kb + chunk * 16;
  const int stA = wave * 1024;
  const int stB = 16384 + wave * 1024;

  auto stage = [&](int slot, int h) {
    const int hb = h << 7;
    char* da = lds + slot * 32768 + stA;
    char* db = lds + slot * 32768 + stB;
#pragma unroll
    for (int i = 0; i < 4; ++i)
      stage16(Ag + hb + (size_t)(i * 32) * Kb, da + i * 4096);
#pragma unroll
    for (int i = 0; i < 4; ++i)
      stage16(Bg + hb + (size_t)(i * 32) * Kb, db + i * 4096);
  };

  i32x4 acc_i[4][4];
  f32x4 acc_f[4][4];
#pragma unroll
  for (int i = 0; i < 4; ++i)
#pragma unroll
    for (int j = 0; j < 4; ++j) {
      acc_i[i][j] = (i32x4)(0);
      acc_f[i][j] = (f32x4){0.f, 0.f, 0.f, 0.f};
    }

  const int nS = Kb >> 7;              // 24
  stage(0, 0);
  // stage the 128 rows x 12 chunk scales (6144 B) into LDS once
  {
    const char* sg = (const char*)stab + (size_t)row0 * 48;
    stage16(sg + tid * 16, lds + 65536 + (tid >> 6) * 1024);
    if (tid < 128)
      stage16(sg + 4096 + tid * 16, lds + 65536 + 4096 + (tid >> 6) * 1024);
  }
  stage(1, 1);
  asm volatile("s_waitcnt vmcnt(8)" ::: "memory");
  __builtin_amdgcn_s_barrier();

  const int fr = lane & 15;
  const int fg = lane >> 4;
  const int xw = (fg ^ (fr & 7)) << 4;
  const int aoff = (wr * 64 + fr) * 128 + xw;
  const int boff = 16384 + (wc * 64 + fr) * 128 + xw;
  const int srow_l = wr * 64 + fg * 4;          // local row base for scales

  for (int t = 0; t < nS; ++t) {
    const int so = (t & 1) * 32768;
    i32x4 af[2][4], bf[2][4];
#pragma unroll
    for (int h = 0; h < 2; ++h) {
      const int hx = h << 6;
#pragma unroll
      for (int mi = 0; mi < 4; ++mi)
        af[h][mi] = *(const i32x4*)(lds + so + ((aoff ^ hx) + mi * 2048));
#pragma unroll
      for (int ni = 0; ni < 4; ++ni)
        bf[h][ni] = *(const i32x4*)(lds + so + ((boff ^ hx) + ni * 2048));
    }
    asm volatile("s_waitcnt lgkmcnt(0)" ::: "memory");
    __builtin_amdgcn_sched_barrier(0);
    __builtin_amdgcn_s_barrier();
    if (t + 2 < nS) stage(t & 1, t + 2);
    __builtin_amdgcn_s_setprio(1);
#pragma unroll
    for (int h = 0; h < 2; ++h)
#pragma unroll
      for (int mi = 0; mi < 4; ++mi)
#pragma unroll
        for (int ni = 0; ni < 4; ++ni)
          acc_i[mi][ni] = __builtin_amdgcn_mfma_i32_16x16x64_i8(
              af[h][mi], bf[h][ni], acc_i[mi][ni], 0, 0, 0);
    __builtin_amdgcn_s_setprio(0);
    if (t & 1) {
      // chunk (t>>1) complete: rescale into f32 accumulators
      const int cc = t >> 1;
#pragma unroll
      for (int mi = 0; mi < 4; ++mi) {
#pragma unroll
        for (int rg = 0; rg < 4; ++rg) {
          float s = *(const float*)(lds + 65536 + ((srow_l + mi * 16 + rg) * 12 + cc) * 4);
#pragma unroll
          for (int ni = 0; ni < 4; ++ni) {
            acc_f[mi][ni][rg] += s * (float)acc_i[mi][ni][rg];
            acc_i[mi][ni][rg] = 0;
          }
        }
      }
    }
    if (t + 2 < nS) asm volatile("s_waitcnt vmcnt(8)" ::: "memory");
    else            asm volatile("s_waitcnt vmcnt(0)" ::: "memory");
    __builtin_amdgcn_s_barrier();
  }

  const int orow = row0 + wr * 64 + fg * 4;
  const int ocol = col0 + wc * 64 + fr;
#pragma unroll
  for (int mi = 0; mi < 4; ++mi) {
#pragma unroll
    for (int ni = 0; ni < 4; ++ni) {
      const int col = ocol + ni * 16;
      const float bv = bias[col];
#pragma unroll
      for (int rg = 0; rg < 4; ++rg) {
        float v = acc_f[mi][ni][rg] + bv;
        Cout[(size_t)(orow + mi * 16 + rg) * N + col] = fmaxf(v, 0.f);
      }
    }
  }
}

// ---------------- launch ----------------

extern "C" void kernel_launch(void* const* d_in, const int* in_sizes, int n_in,
                              void* d_out, int out_size, void* d_ws, size_t ws_size,
                              hipStream_t stream) {
  const float* x  = (const float*)d_in[0];
  const float* w1 = (const float*)d_in[1];
  const float* b1 = (const float*)d_in[2];
  const float* w2 = (const float*)d_in[3];
  const float* b2 = (const float*)d_in[4];
  const float* as = (const float*)d_in[5];

  const int Mrows = 64 * 196;   // 12544
  const int D = 768, H = 3072;

  char* ws = (char*)d_ws;
  size_t off = 0;
  auto align256 = [](size_t v) { return (v + 255) & ~(size_t)255; };
  unsigned* mx = (unsigned*)(ws + off); off += 256;
  char* xq8    = (char*)(ws + off);     off += align256((size_t)Mrows * D);
  char* w1q8   = (char*)(ws + off);     off += align256((size_t)H * D);
  char* w2q8   = (char*)(ws + off);     off += align256((size_t)D * H);
  float* b1i = (float*)(ws + off); off += align256((size_t)H * 4);
  float* b2i = (float*)(ws + off); off += align256((size_t)D * 4);
  float* stab = (float*)(ws + off); off += align256((size_t)Mrows * 12 * 4);
  unsigned char* hq = (unsigned char*)(ws + off); off += align256((size_t)Mrows * H);
  if (off > ws_size) return;

  float* out = (float*)d_out;
  float* s_out = out + (out_size - 1);

  hipMemsetAsync(mx, 0, 8, stream);

  const int nw4 = H * D / 4;
  prep_kernel<<<dim3(1024, 3), dim3(256), 0, stream>>>(
      (const float4*)x, (uchar4*)xq8, Mrows * D / 4,
      (const float4*)w1, (const float4*)w2, nw4, mx);
  quantwb_kernel<<<dim3(1024, 3), dim3(256), 0, stream>>>(
      (const float4*)w1, (const float4*)w2, (uchar4*)w1q8, (uchar4*)w2q8,
      b1, b2, b1i, b2i, mx, as, s_out, nw4, H, D);

  // fc1: int8 256x256, 588 blocks, Kb = 768
  gemm_fc1<<<dim3((Mrows / 256) * (H / 256)), dim3(512), 0, stream>>>(
      xq8, w1q8, b1i, hq, stab, Mrows, H, D);
  // fc2: int8 128x128 with per-chunk rescale, 588 blocks, Kb = 3072
  gemm_fc2<<<dim3((Mrows / 128) * (D / 128)), dim3(256), 0, stream>>>(
      (const char*)hq, w2q8, b2i, stab, out, Mrows, D, H);
}

// Round 10
// 157.268 us; speedup vs baseline: 1.2065x; 1.2065x over previous
//
#include <hip/hip_runtime.h>
#include <hip/hip_bf16.h>
#include <type_traits>

typedef __attribute__((ext_vector_type(8))) short bf16x8;
typedef __attribute__((ext_vector_type(4))) float f32x4;
typedef __attribute__((ext_vector_type(4))) int   i32x4;

static __device__ __forceinline__ void stage16(const void* g, void* l) {
  __builtin_amdgcn_global_load_lds((const __attribute__((address_space(1))) void*)g,
                                   (__attribute__((address_space(3))) void*)l,
                                   16, 0, 0);
}

// ---------------- prep ----------------
// y==0 (1024 blocks): x f32 -> int8. y==1/2 (96 blocks): maxabs(w1/w2).
__global__ void prep_kernel(const float4* __restrict__ x, uchar4* __restrict__ xq, int n4x,
                            const float4* __restrict__ w1, const float4* __restrict__ w2,
                            int n4w, unsigned* __restrict__ mx) {
  if (blockIdx.y == 0) {
    const int stride = gridDim.x * blockDim.x;
    for (int i = blockIdx.x * blockDim.x + threadIdx.x; i < n4x; i += stride) {
      float4 v = x[i];
      uchar4 o;
      o.x = (unsigned char)(char)fminf(fmaxf(v.x, -127.f), 127.f);
      o.y = (unsigned char)(char)fminf(fmaxf(v.y, -127.f), 127.f);
      o.z = (unsigned char)(char)fminf(fmaxf(v.z, -127.f), 127.f);
      o.w = (unsigned char)(char)fminf(fmaxf(v.w, -127.f), 127.f);
      xq[i] = o;
    }
  } else {
    if (blockIdx.x >= 96) return;
    __shared__ unsigned red[4];
    const float4* w = (blockIdx.y == 1) ? w1 : w2;
    unsigned m = 0;
    const int stride = 96 * 256;
    for (int i = blockIdx.x * blockDim.x + threadIdx.x; i < n4w; i += stride) {
      float4 v = w[i];
      unsigned a;
      a = __float_as_uint(fabsf(v.x)); m = m > a ? m : a;
      a = __float_as_uint(fabsf(v.y)); m = m > a ? m : a;
      a = __float_as_uint(fabsf(v.z)); m = m > a ? m : a;
      a = __float_as_uint(fabsf(v.w)); m = m > a ? m : a;
    }
#pragma unroll
    for (int off = 32; off > 0; off >>= 1) {
      unsigned t = (unsigned)__shfl_down((int)m, off, 64);
      m = m > t ? m : t;
    }
    if ((threadIdx.x & 63) == 0) red[threadIdx.x >> 6] = m;
    __syncthreads();
    if (threadIdx.x == 0) {
      unsigned t0 = red[0] > red[1] ? red[0] : red[1];
      unsigned t1 = red[2] > red[3] ? red[2] : red[3];
      atomicMax(mx + blockIdx.y - 1, t0 > t1 ? t0 : t1);
    }
  }
}

// y==0: w1 -> int8 ; y==1: w2 -> int8 ; y==2 blk0: biases + final scale.
__global__ void quantwb_kernel(const float4* __restrict__ w1, const float4* __restrict__ w2,
                               uchar4* __restrict__ w1q, uchar4* __restrict__ w2q,
                               const float* __restrict__ b1, const float* __restrict__ b2,
                               float* __restrict__ b1i, float* __restrict__ b2i,
                               const unsigned* __restrict__ mx, const float* __restrict__ a_s,
                               float* __restrict__ s_out, int n4, int H, int D) {
  const float ws1 = __uint_as_float(mx[0]) / 127.0f;
  const float ws2 = __uint_as_float(mx[1]) / 127.0f;
  const int stride = gridDim.x * blockDim.x;
  if (blockIdx.y <= 1) {
    const float4* w = blockIdx.y ? w2 : w1;
    uchar4* wq = blockIdx.y ? w2q : w1q;
    const float ws = blockIdx.y ? ws2 : ws1;
    for (int i = blockIdx.x * blockDim.x + threadIdx.x; i < n4; i += stride) {
      float4 v = w[i];
      uchar4 o;
      o.x = (unsigned char)(char)fminf(fmaxf(rintf(v.x / ws), -127.f), 127.f);
      o.y = (unsigned char)(char)fminf(fmaxf(rintf(v.y / ws), -127.f), 127.f);
      o.z = (unsigned char)(char)fminf(fmaxf(rintf(v.z / ws), -127.f), 127.f);
      o.w = (unsigned char)(char)fminf(fmaxf(rintf(v.w / ws), -127.f), 127.f);
      wq[i] = o;
    }
  } else {
    if (blockIdx.x != 0) return;
    const float s0 = a_s[0];
    const float s1 = s0 * ws1;
    const float d1 = ws1 * s0;
    const float d2 = ws2 * s1;
    if (threadIdx.x == 0) s_out[0] = s1 * ws2;
    for (int i = threadIdx.x; i < H; i += blockDim.x) {
      float q = rintf(b1[i] / d1);
      b1i[i] = fminf(fmaxf(q, -2147483647.f), 2147483647.f);
    }
    for (int i = threadIdx.x; i < D; i += blockDim.x) {
      float q = rintf(b2[i] / d2);
      b2i[i] = fminf(fmaxf(q, -2147483647.f), 2147483647.f);
    }
  }
}

// ---------------- fc1: 256x256 int8 GEMM, 8 waves, 2-slot BK=128B ----------------
// Epilogue: h = acc + b1 (exact), per-row-chunk (256 cols) int8 quantization;
// writes h_q (i8) + stab[row][12] (s_chunk = chunkmax/127).

__global__ __launch_bounds__(512, 2) void gemm_fc1(
    const char* __restrict__ A, const char* __restrict__ Bt,
    const float* __restrict__ b1f, unsigned char* __restrict__ hq,
    float* __restrict__ stab, int M, int N, int Kb)
{
  __shared__ char lds[2 * 65536];
  const int tid = threadIdx.x;
  const int lane = tid & 63;
  const int wave = tid >> 6;
  const int wr = wave >> 2;
  const int wc = wave & 3;

  const int nbx = M / 256;             // 49
  const int nby = N / 256;             // 12
  const int bandSize = 16 * nby;
  const int b = blockIdx.x / bandSize;
  const int local = blockIdx.x - b * bandSize;
  const int r0 = b * 16;
  const int rn = min(16, nbx - r0);
  const int c = local / rn;
  const int r = r0 + (local - c * rn);
  const int row0 = r * 256;
  const int col0 = c * 256;

  const int srow = tid >> 3;
  const int chunk = (tid & 7) ^ (srow & 7);
  const char* Ag = A + (size_t)(row0 + srow) * Kb + chunk * 16;
  const char* Bg = Bt + (size_t)(col0 + srow) * Kb + chunk * 16;
  const int wb = wave * 1024;

  auto stage = [&](int slot, int st) {
    char* da = lds + slot * 65536 + wb;
    char* db = lds + slot * 65536 + 32768 + wb;
    const int ko = st << 7;
#pragma unroll
    for (int i = 0; i < 4; ++i)
      stage16(Ag + ko + (size_t)(i * 64) * Kb, da + i * 8192);
#pragma unroll
    for (int i = 0; i < 4; ++i)
      stage16(Bg + ko + (size_t)(i * 64) * Kb, db + i * 8192);
  };

  i32x4 acc[8][4];
#pragma unroll
  for (int i = 0; i < 8; ++i)
#pragma unroll
    for (int j = 0; j < 4; ++j) acc[i][j] = (i32x4)(0);

  const int nS = Kb >> 7;              // 6
  stage(0, 0);
  stage(1, 1);
  asm volatile("s_waitcnt vmcnt(8)" ::: "memory");
  __builtin_amdgcn_s_barrier();

  const int fr = lane & 15;
  const int fg = lane >> 4;
  const int ch0 = ((fg ^ (fr & 7)) & 7) << 4;
  const int Abase = (wr * 128 + fr) * 128;
  const int Bbase = 32768 + (wc * 64 + fr) * 128;

  for (int t = 0; t < nS; ++t) {
    const int so = (t & 1) << 16;
    i32x4 af[8], bf[4];
#pragma unroll
    for (int mf = 0; mf < 8; ++mf) af[mf] = *(const i32x4*)(lds + so + Abase + mf * 2048 + ch0);
#pragma unroll
    for (int nf = 0; nf < 4; ++nf) bf[nf] = *(const i32x4*)(lds + so + Bbase + nf * 2048 + ch0);
    __builtin_amdgcn_s_setprio(1);
#pragma unroll
    for (int mf = 0; mf < 8; ++mf)
#pragma unroll
      for (int nf = 0; nf < 4; ++nf)
        acc[mf][nf] = __builtin_amdgcn_mfma_i32_16x16x64_i8(af[mf], bf[nf], acc[mf][nf], 0, 0, 0);
    __builtin_amdgcn_s_setprio(0);
#pragma unroll
    for (int mf = 0; mf < 8; ++mf) af[mf] = *(const i32x4*)(lds + so + Abase + mf * 2048 + (ch0 ^ 64));
#pragma unroll
    for (int nf = 0; nf < 4; ++nf) bf[nf] = *(const i32x4*)(lds + so + Bbase + nf * 2048 + (ch0 ^ 64));
    asm volatile("s_waitcnt lgkmcnt(0)" ::: "memory");
    __builtin_amdgcn_sched_barrier(0);
    __builtin_amdgcn_s_barrier();
    const bool st = (t + 2 < nS);
    if (st) stage(t & 1, t + 2);
    __builtin_amdgcn_s_setprio(1);
#pragma unroll
    for (int mf = 0; mf < 8; ++mf)
#pragma unroll
      for (int nf = 0; nf < 4; ++nf)
        acc[mf][nf] = __builtin_amdgcn_mfma_i32_16x16x64_i8(af[mf], bf[nf], acc[mf][nf], 0, 0, 0);
    __builtin_amdgcn_s_setprio(0);
    if (t + 1 < nS) {
      if (st) asm volatile("s_waitcnt vmcnt(8)" ::: "memory");
      else    asm volatile("s_waitcnt vmcnt(0)" ::: "memory");
      __builtin_amdgcn_s_barrier();
    }
  }

  // ---- epilogue: per-row-chunk int8 quantization ----
  __syncthreads();
  float* rowtab = (float*)lds;         // [256][4]
  const int orow_l = wr * 128 + fg * 4;
  const int ocol = col0 + wc * 64 + fr;
  float bv[4];
#pragma unroll
  for (int nf = 0; nf < 4; ++nf) bv[nf] = b1f[ocol + nf * 16];

#pragma unroll
  for (int mf = 0; mf < 8; ++mf) {
    float rmax[4] = {0.f, 0.f, 0.f, 0.f};
#pragma unroll
    for (int nf = 0; nf < 4; ++nf)
#pragma unroll
      for (int rg = 0; rg < 4; ++rg) {
        float v = (float)acc[mf][nf][rg] + bv[nf];
        rmax[rg] = fmaxf(rmax[rg], fabsf(v));
      }
#pragma unroll
    for (int rg = 0; rg < 4; ++rg) {
#pragma unroll
      for (int m = 1; m <= 8; m <<= 1)
        rmax[rg] = fmaxf(rmax[rg], __shfl_xor(rmax[rg], m, 64));
      if (fr == 0) rowtab[(orow_l + mf * 16 + rg) * 4 + wc] = rmax[rg];
    }
  }
  __syncthreads();
#pragma unroll
  for (int mf = 0; mf < 8; ++mf) {
#pragma unroll
    for (int rg = 0; rg < 4; ++rg) {
      const int lr = orow_l + mf * 16 + rg;
      float4 rt = *(const float4*)&rowtab[lr * 4];
      float rm = fmaxf(fmaxf(rt.x, rt.y), fmaxf(rt.z, rt.w));
      float inv = rm > 0.f ? 127.f / rm : 0.f;
      if (wc == 0 && fr == 0) stab[(size_t)(row0 + lr) * 12 + c] = rm * (1.f / 127.f);
#pragma unroll
      for (int nf = 0; nf < 4; ++nf) {
        float v = (float)acc[mf][nf][rg] + bv[nf];
        hq[(size_t)(row0 + lr) * N + ocol + nf * 16] =
            (unsigned char)(signed char)(int)rintf(v * inv);
      }
    }
  }
}

// ---------------- requant: per-chunk h_q -> per-row h_q' + srow ----------------
// v-th 16B vector: row = v/192, chunk = (v%192)/16. s_row = max(stab[row][0..11]);
// h_q' = rint(h_q * s_chunk/s_row)  (|.| <= 127 since s_chunk <= s_row).
__global__ void requant_kernel(const uint4* __restrict__ hq, uint4* __restrict__ hq2,
                               const float* __restrict__ stab, float* __restrict__ srow,
                               int nvec) {
  const int stride = gridDim.x * blockDim.x;
  for (int v = blockIdx.x * blockDim.x + threadIdx.x; v < nvec; v += stride) {
    const int row = v / 192;
    const int j = v - row * 192;
    const int chunk = j >> 4;
    const float* st = stab + row * 12;
    float sr = st[0];
#pragma unroll
    for (int i = 1; i < 12; ++i) sr = fmaxf(sr, st[i]);
    const float ratio = sr > 0.f ? st[chunk] / sr : 0.f;
    if (j == 0) srow[row] = sr;
    uint4 in = hq[v], out;
    unsigned* ip = (unsigned*)&in;
    unsigned* op = (unsigned*)&out;
#pragma unroll
    for (int w = 0; w < 4; ++w) {
      unsigned r = 0;
#pragma unroll
      for (int k = 0; k < 4; ++k) {
        int q = (int)(signed char)((ip[w] >> (k * 8)) & 0xFF);
        int nq = (int)rintf((float)q * ratio);
        r |= ((unsigned)nq & 0xFF) << (k * 8);
      }
      op[w] = r;
    }
    hq2[v] = out;
  }
}

// ---------------- fc2: 128x128 pure int8 GEMM (R8-proven loop, i8 types) ----------------
// A = h_q' (i8, one scale/row), B = w2_int (i8 exact). int32 accum over full K
// (max |sum| ~5e7 << 2^31, exact). Epilogue: out = srow[r]*acc + b2int, ReLU.

__global__ __launch_bounds__(256) void gemm_fc2(
    const char* __restrict__ A, const char* __restrict__ Bt,
    const float* __restrict__ bias, const float* __restrict__ srow,
    float* __restrict__ Cout, int M, int N, int Kb)
{
  __shared__ char lds[2 * 32768];
  const int tid = threadIdx.x;
  const int lane = tid & 63;
  const int wave = tid >> 6;
  const int wr = wave >> 1;
  const int wc = wave & 1;

  const int nbx = M / 128;
  const int nby = N / 128;
  const int nwg = nbx * nby;
  const int q8 = nwg >> 3, r8 = nwg & 7;
  const int xcd = blockIdx.x & 7, bidx = blockIdx.x >> 3;
  const int wg = (xcd < r8 ? xcd * (q8 + 1) : r8 * (q8 + 1) + (xcd - r8) * q8) + bidx;
  const int r = wg / nby;
  const int c = wg % nby;
  const int row0 = r * 128;
  const int col0 = c * 128;

  const int srw = tid >> 3;
  const int chunk = (tid & 7) ^ (srw & 7);
  const char* Ag = A + (size_t)(row0 + srw) * Kb + chunk * 16;
  const char* Bg = Bt + (size_t)(col0 + srw) * Kb + chunk * 16;
  const int stA = wave * 1024;
  const int stB = 16384 + wave * 1024;

  auto stage = [&](int slot, int h) {
    const int hb = h << 7;
    char* da = lds + slot * 32768 + stA;
    char* db = lds + slot * 32768 + stB;
#pragma unroll
    for (int i = 0; i < 4; ++i)
      stage16(Ag + hb + (size_t)(i * 32) * Kb, da + i * 4096);
#pragma unroll
    for (int i = 0; i < 4; ++i)
      stage16(Bg + hb + (size_t)(i * 32) * Kb, db + i * 4096);
  };

  i32x4 acc[4][4];
#pragma unroll
  for (int i = 0; i < 4; ++i)
#pragma unroll
    for (int j = 0; j < 4; ++j) acc[i][j] = (i32x4)(0);

  const int nS = Kb >> 7;              // 24
  stage(0, 0);
  stage(1, 1);
  asm volatile("s_waitcnt vmcnt(8)" ::: "memory");
  __builtin_amdgcn_s_barrier();

  const int fr = lane & 15;
  const int fg = lane >> 4;
  const int xw = (fg ^ (fr & 7)) << 4;
  const int aoff = (wr * 64 + fr) * 128 + xw;
  const int boff = 16384 + (wc * 64 + fr) * 128 + xw;

  for (int t = 0; t < nS; ++t) {
    const int so = (t & 1) * 32768;
    i32x4 af[2][4], bf[2][4];
#pragma unroll
    for (int h = 0; h < 2; ++h) {
      const int hx = h << 6;
#pragma unroll
      for (int mi = 0; mi < 4; ++mi)
        af[h][mi] = *(const i32x4*)(lds + so + ((aoff ^ hx) + mi * 2048));
#pragma unroll
      for (int ni = 0; ni < 4; ++ni)
        bf[h][ni] = *(const i32x4*)(lds + so + ((boff ^ hx) + ni * 2048));
    }
    asm volatile("s_waitcnt lgkmcnt(0)" ::: "memory");
    __builtin_amdgcn_sched_barrier(0);
    __builtin_amdgcn_s_barrier();
    if (t + 2 < nS) stage(t & 1, t + 2);
    __builtin_amdgcn_s_setprio(1);
#pragma unroll
    for (int h = 0; h < 2; ++h)
#pragma unroll
      for (int mi = 0; mi < 4; ++mi)
#pragma unroll
        for (int ni = 0; ni < 4; ++ni)
          acc[mi][ni] = __builtin_amdgcn_mfma_i32_16x16x64_i8(
              af[h][mi], bf[h][ni], acc[mi][ni], 0, 0, 0);
    __builtin_amdgcn_s_setprio(0);
    if (t + 2 < nS) asm volatile("s_waitcnt vmcnt(8)" ::: "memory");
    else            asm volatile("s_waitcnt vmcnt(0)" ::: "memory");
    __builtin_amdgcn_s_barrier();
  }

  const int orow = row0 + wr * 64 + fg * 4;
  const int ocol = col0 + wc * 64 + fr;
#pragma unroll
  for (int mi = 0; mi < 4; ++mi) {
    float sr[4];
#pragma unroll
    for (int rg = 0; rg < 4; ++rg) sr[rg] = srow[orow + mi * 16 + rg];
#pragma unroll
    for (int ni = 0; ni < 4; ++ni) {
      const int col = ocol + ni * 16;
      const float bv = bias[col];
#pragma unroll
      for (int rg = 0; rg < 4; ++rg) {
        float v = sr[rg] * (float)acc[mi][ni][rg] + bv;
        Cout[(size_t)(orow + mi * 16 + rg) * N + col] = fmaxf(v, 0.f);
      }
    }
  }
}

// ---------------- launch ----------------

extern "C" void kernel_launch(void* const* d_in, const int* in_sizes, int n_in,
                              void* d_out, int out_size, void* d_ws, size_t ws_size,
                              hipStream_t stream) {
  const float* x  = (const float*)d_in[0];
  const float* w1 = (const float*)d_in[1];
  const float* b1 = (const float*)d_in[2];
  const float* w2 = (const float*)d_in[3];
  const float* b2 = (const float*)d_in[4];
  const float* as = (const float*)d_in[5];

  const int Mrows = 64 * 196;   // 12544
  const int D = 768, H = 3072;

  char* ws = (char*)d_ws;
  size_t off = 0;
  auto align256 = [](size_t v) { return (v + 255) & ~(size_t)255; };
  unsigned* mx = (unsigned*)(ws + off); off += 256;
  char* xq8    = (char*)(ws + off);     off += align256((size_t)Mrows * D);
  char* w1q8   = (char*)(ws + off);     off += align256((size_t)H * D);
  char* w2q8   = (char*)(ws + off);     off += align256((size_t)D * H);
  float* b1i = (float*)(ws + off); off += align256((size_t)H * 4);
  float* b2i = (float*)(ws + off); off += align256((size_t)D * 4);
  float* stab = (float*)(ws + off); off += align256((size_t)Mrows * 12 * 4);
  float* srow = (float*)(ws + off); off += align256((size_t)Mrows * 4);
  unsigned char* hq  = (unsigned char*)(ws + off); off += align256((size_t)Mrows * H);
  unsigned char* hq2 = (unsigned char*)(ws + off); off += align256((size_t)Mrows * H);
  if (off > ws_size) return;

  float* out = (float*)d_out;
  float* s_out = out + (out_size - 1);

  hipMemsetAsync(mx, 0, 8, stream);

  const int nw4 = H * D / 4;
  prep_kernel<<<dim3(1024, 3), dim3(256), 0, stream>>>(
      (const float4*)x, (uchar4*)xq8, Mrows * D / 4,
      (const float4*)w1, (const float4*)w2, nw4, mx);
  quantwb_kernel<<<dim3(1024, 3), dim3(256), 0, stream>>>(
      (const float4*)w1, (const float4*)w2, (uchar4*)w1q8, (uchar4*)w2q8,
      b1, b2, b1i, b2i, mx, as, s_out, nw4, H, D);

  // fc1: int8 256x256, 588 blocks, Kb = 768
  gemm_fc1<<<dim3((Mrows / 256) * (H / 256)), dim3(512), 0, stream>>>(
      xq8, w1q8, b1i, hq, stab, Mrows, H, D);
  // requant: per-chunk -> per-row scales (2.41M 16B vectors)
  requant_kernel<<<dim3(2048), dim3(256), 0, stream>>>(
      (const uint4*)hq, (uint4*)hq2, stab, srow, Mrows * H / 16);
  // fc2: pure int8 128x128, 588 blocks, Kb = 3072
  gemm_fc2<<<dim3((Mrows / 128) * (D / 128)), dim3(256), 0, stream>>>(
      (const char*)hq2, w2q8, b2i, srow, out, Mrows, D, H);
}

// Round 11
// 148.901 us; speedup vs baseline: 1.2742x; 1.0562x over previous
//
#include <hip/hip_runtime.h>
#include <hip/hip_bf16.h>
#include <type_traits>

typedef __attribute__((ext_vector_type(4))) float f32x4;
typedef __attribute__((ext_vector_type(4))) int   i32x4;

static __device__ __forceinline__ void stage16(const void* g, void* l) {
  __builtin_amdgcn_global_load_lds((const __attribute__((address_space(1))) void*)g,
                                   (__attribute__((address_space(3))) void*)l,
                                   16, 0, 0);
}

// ---------------- prep ----------------
// y==0 (1024 blocks): x f32 -> int8. y==1/2 (96 blocks): maxabs(w1/w2).
__global__ void prep_kernel(const float4* __restrict__ x, uchar4* __restrict__ xq, int n4x,
                            const float4* __restrict__ w1, const float4* __restrict__ w2,
                            int n4w, unsigned* __restrict__ mx) {
  if (blockIdx.y == 0) {
    const int stride = gridDim.x * blockDim.x;
    for (int i = blockIdx.x * blockDim.x + threadIdx.x; i < n4x; i += stride) {
      float4 v = x[i];
      uchar4 o;
      o.x = (unsigned char)(char)fminf(fmaxf(v.x, -127.f), 127.f);
      o.y = (unsigned char)(char)fminf(fmaxf(v.y, -127.f), 127.f);
      o.z = (unsigned char)(char)fminf(fmaxf(v.z, -127.f), 127.f);
      o.w = (unsigned char)(char)fminf(fmaxf(v.w, -127.f), 127.f);
      xq[i] = o;
    }
  } else {
    if (blockIdx.x >= 96) return;
    __shared__ unsigned red[4];
    const float4* w = (blockIdx.y == 1) ? w1 : w2;
    unsigned m = 0;
    const int stride = 96 * 256;
    for (int i = blockIdx.x * blockDim.x + threadIdx.x; i < n4w; i += stride) {
      float4 v = w[i];
      unsigned a;
      a = __float_as_uint(fabsf(v.x)); m = m > a ? m : a;
      a = __float_as_uint(fabsf(v.y)); m = m > a ? m : a;
      a = __float_as_uint(fabsf(v.z)); m = m > a ? m : a;
      a = __float_as_uint(fabsf(v.w)); m = m > a ? m : a;
    }
#pragma unroll
    for (int off = 32; off > 0; off >>= 1) {
      unsigned t = (unsigned)__shfl_down((int)m, off, 64);
      m = m > t ? m : t;
    }
    if ((threadIdx.x & 63) == 0) red[threadIdx.x >> 6] = m;
    __syncthreads();
    if (threadIdx.x == 0) {
      unsigned t0 = red[0] > red[1] ? red[0] : red[1];
      unsigned t1 = red[2] > red[3] ? red[2] : red[3];
      atomicMax(mx + blockIdx.y - 1, t0 > t1 ? t0 : t1);
    }
  }
}

// y==0: w1 -> int8 ; y==1: w2 -> int8 ; y==2 blk0: biases + final scale.
__global__ void quantwb_kernel(const float4* __restrict__ w1, const float4* __restrict__ w2,
                               uchar4* __restrict__ w1q, uchar4* __restrict__ w2q,
                               const float* __restrict__ b1, const float* __restrict__ b2,
                               float* __restrict__ b1i, float* __restrict__ b2i,
                               const unsigned* __restrict__ mx, const float* __restrict__ a_s,
                               float* __restrict__ s_out, int n4, int H, int D) {
  const float ws1 = __uint_as_float(mx[0]) / 127.0f;
  const float ws2 = __uint_as_float(mx[1]) / 127.0f;
  const int stride = gridDim.x * blockDim.x;
  if (blockIdx.y <= 1) {
    const float4* w = blockIdx.y ? w2 : w1;
    uchar4* wq = blockIdx.y ? w2q : w1q;
    const float ws = blockIdx.y ? ws2 : ws1;
    for (int i = blockIdx.x * blockDim.x + threadIdx.x; i < n4; i += stride) {
      float4 v = w[i];
      uchar4 o;
      o.x = (unsigned char)(char)fminf(fmaxf(rintf(v.x / ws), -127.f), 127.f);
      o.y = (unsigned char)(char)fminf(fmaxf(rintf(v.y / ws), -127.f), 127.f);
      o.z = (unsigned char)(char)fminf(fmaxf(rintf(v.z / ws), -127.f), 127.f);
      o.w = (unsigned char)(char)fminf(fmaxf(rintf(v.w / ws), -127.f), 127.f);
      wq[i] = o;
    }
  } else {
    if (blockIdx.x != 0) return;
    const float s0 = a_s[0];
    const float s1 = s0 * ws1;
    const float d1 = ws1 * s0;
    const float d2 = ws2 * s1;
    if (threadIdx.x == 0) s_out[0] = s1 * ws2;
    for (int i = threadIdx.x; i < H; i += blockDim.x) {
      float q = rintf(b1[i] / d1);
      b1i[i] = fminf(fmaxf(q, -2147483647.f), 2147483647.f);
    }
    for (int i = threadIdx.x; i < D; i += blockDim.x) {
      float q = rintf(b2[i] / d2);
      b2i[i] = fminf(fmaxf(q, -2147483647.f), 2147483647.f);
    }
  }
}

// ---------------- fc1: 128x128 int8 GEMM, 4 waves, 2-slot BK=128B, 2 blocks/CU ----
// Epilogue: h = acc + b1 (exact int32), per-row-chunk (128 cols) int8 quant,
// staged through LDS for coalesced stores. stab[row][24] = chunkmax/127.

__global__ __launch_bounds__(256) void gemm_fc1(
    const char* __restrict__ A, const char* __restrict__ Bt,
    const float* __restrict__ b1f, unsigned char* __restrict__ hq,
    float* __restrict__ stab, int M, int N, int Kb)
{
  __shared__ char lds[2 * 32768 + 1024];   // 2 slots; epilogue reuses slot0 + rowtab
  const int tid = threadIdx.x;
  const int lane = tid & 63;
  const int wave = tid >> 6;
  const int wr = wave >> 1;
  const int wc = wave & 1;

  // 16-row-tile bands, col-major within band (A-band ~1.5MB L2-resident)
  const int nbx = M / 128;             // 98
  const int nby = N / 128;             // 24
  const int bandSize = 16 * nby;
  const int b = blockIdx.x / bandSize;
  const int local = blockIdx.x - b * bandSize;
  const int r0 = b * 16;
  const int rn = min(16, nbx - r0);
  const int c = local / rn;
  const int r = r0 + (local - c * rn);
  const int row0 = r * 128;
  const int col0 = c * 128;

  const int srw = tid >> 3;
  const int chunk = (tid & 7) ^ (srw & 7);
  const char* Ag = A + (size_t)(row0 + srw) * Kb + chunk * 16;
  const char* Bg = Bt + (size_t)(col0 + srw) * Kb + chunk * 16;
  const int stA = wave * 1024;
  const int stB = 16384 + wave * 1024;

  auto stage = [&](int slot, int h) {
    const int hb = h << 7;
    char* da = lds + slot * 32768 + stA;
    char* db = lds + slot * 32768 + stB;
#pragma unroll
    for (int i = 0; i < 4; ++i)
      stage16(Ag + hb + (size_t)(i * 32) * Kb, da + i * 4096);
#pragma unroll
    for (int i = 0; i < 4; ++i)
      stage16(Bg + hb + (size_t)(i * 32) * Kb, db + i * 4096);
  };

  i32x4 acc[4][4];
#pragma unroll
  for (int i = 0; i < 4; ++i)
#pragma unroll
    for (int j = 0; j < 4; ++j) acc[i][j] = (i32x4)(0);

  const int nS = Kb >> 7;              // 6
  stage(0, 0);
  stage(1, 1);
  asm volatile("s_waitcnt vmcnt(8)" ::: "memory");
  __builtin_amdgcn_s_barrier();

  const int fr = lane & 15;
  const int fg = lane >> 4;
  const int xw = (fg ^ (fr & 7)) << 4;
  const int aoff = (wr * 64 + fr) * 128 + xw;
  const int boff = 16384 + (wc * 64 + fr) * 128 + xw;

  for (int t = 0; t < nS; ++t) {
    const int so = (t & 1) * 32768;
    i32x4 af[2][4], bf[2][4];
#pragma unroll
    for (int h = 0; h < 2; ++h) {
      const int hx = h << 6;
#pragma unroll
      for (int mi = 0; mi < 4; ++mi)
        af[h][mi] = *(const i32x4*)(lds + so + ((aoff ^ hx) + mi * 2048));
#pragma unroll
      for (int ni = 0; ni < 4; ++ni)
        bf[h][ni] = *(const i32x4*)(lds + so + ((boff ^ hx) + ni * 2048));
    }
    asm volatile("s_waitcnt lgkmcnt(0)" ::: "memory");
    __builtin_amdgcn_sched_barrier(0);
    __builtin_amdgcn_s_barrier();
    if (t + 2 < nS) stage(t & 1, t + 2);
    __builtin_amdgcn_s_setprio(1);
#pragma unroll
    for (int h = 0; h < 2; ++h)
#pragma unroll
      for (int mi = 0; mi < 4; ++mi)
#pragma unroll
        for (int ni = 0; ni < 4; ++ni)
          acc[mi][ni] = __builtin_amdgcn_mfma_i32_16x16x64_i8(
              af[h][mi], bf[h][ni], acc[mi][ni], 0, 0, 0);
    __builtin_amdgcn_s_setprio(0);
    if (t + 2 < nS) asm volatile("s_waitcnt vmcnt(8)" ::: "memory");
    else            asm volatile("s_waitcnt vmcnt(0)" ::: "memory");
    __builtin_amdgcn_s_barrier();
  }

  // ---- epilogue: per-row-chunk quant, LDS-staged coalesced output ----
  __syncthreads();
  unsigned char* ostage = (unsigned char*)lds;       // 16 KB (slot0 reuse)
  float* rowtab = (float*)(lds + 65536);             // [128][2]
  const int orow_l = wr * 64 + fg * 4;
  const int ocol_l = wc * 64 + fr;
  float bv[4];
#pragma unroll
  for (int nf = 0; nf < 4; ++nf) bv[nf] = b1f[col0 + ocol_l + nf * 16];

  // phase 1: per-row max over this tile
#pragma unroll
  for (int mf = 0; mf < 4; ++mf) {
    float rmax[4] = {0.f, 0.f, 0.f, 0.f};
#pragma unroll
    for (int nf = 0; nf < 4; ++nf)
#pragma unroll
      for (int rg = 0; rg < 4; ++rg) {
        float v = (float)acc[mf][nf][rg] + bv[nf];
        rmax[rg] = fmaxf(rmax[rg], fabsf(v));
      }
#pragma unroll
    for (int rg = 0; rg < 4; ++rg) {
#pragma unroll
      for (int m = 1; m <= 8; m <<= 1)
        rmax[rg] = fmaxf(rmax[rg], __shfl_xor(rmax[rg], m, 64));
      if (fr == 0) rowtab[(orow_l + mf * 16 + rg) * 2 + wc] = rmax[rg];
    }
  }
  __syncthreads();
  // phase 2: quantize into LDS stage (+ stab write, one lane per row)
#pragma unroll
  for (int mf = 0; mf < 4; ++mf) {
#pragma unroll
    for (int rg = 0; rg < 4; ++rg) {
      const int lr = orow_l + mf * 16 + rg;
      float rm = fmaxf(rowtab[lr * 2], rowtab[lr * 2 + 1]);
      float inv = rm > 0.f ? 127.f / rm : 0.f;
      if (wc == 0 && fr == 0) stab[(size_t)(row0 + lr) * 24 + c] = rm * (1.f / 127.f);
#pragma unroll
      for (int nf = 0; nf < 4; ++nf) {
        float v = (float)acc[mf][nf][rg] + bv[nf];
        ostage[lr * 128 + ocol_l + nf * 16] = (unsigned char)(signed char)(int)rintf(v * inv);
      }
    }
  }
  __syncthreads();
  // phase 3: coalesced copy out (8 rows x 128B contiguous per instruction)
#pragma unroll
  for (int v = 0; v < 4; ++v) {
    const int idx = tid + v * 256;
    const int lr = idx >> 3, cc = idx & 7;
    *(uint4*)(hq + (size_t)(row0 + lr) * N + col0 + cc * 16) =
        *(const uint4*)(ostage + lr * 128 + cc * 16);
  }
}

// ---------------- requant: per-chunk h_q -> per-row h_q' + srow ----------------
// 4 rows/block; scale row (24 floats, L2-hot) read once per row.
__global__ void requant_kernel(const uint4* __restrict__ hq, uint4* __restrict__ hq2,
                               const float* __restrict__ stab, float* __restrict__ srow,
                               int Mrows) {
  const int row = blockIdx.x * 4 + (threadIdx.x >> 6);
  if (row >= Mrows) return;
  const int lane = threadIdx.x & 63;
  const float* st = stab + (size_t)row * 24;
  float sr = 0.f;
#pragma unroll
  for (int i = 0; i < 24; ++i) sr = fmaxf(sr, st[i]);
  if (lane == 0) srow[row] = sr;
  const float rinv = sr > 0.f ? 1.f / sr : 0.f;
  const uint4* in = hq + (size_t)row * 192;
  uint4* outp = hq2 + (size_t)row * 192;
#pragma unroll
  for (int it = 0; it < 3; ++it) {
    const int j = lane + it * 64;            // 16B vector within row; chunk = j>>3
    const float ratio = st[j >> 3] * rinv;
    uint4 iv = in[j], ov;
    unsigned* ip = (unsigned*)&iv;
    unsigned* op = (unsigned*)&ov;
#pragma unroll
    for (int w = 0; w < 4; ++w) {
      unsigned rr = 0;
#pragma unroll
      for (int k = 0; k < 4; ++k) {
        int q = (int)(signed char)((ip[w] >> (k * 8)) & 0xFF);
        int nq = (int)rintf((float)q * ratio);
        rr |= ((unsigned)nq & 0xFF) << (k * 8);
      }
      op[w] = rr;
    }
    outp[j] = ov;
  }
}

// ---------------- fc2: 128x128 pure int8 GEMM (R8-proven loop) ----------------
__global__ __launch_bounds__(256) void gemm_fc2(
    const char* __restrict__ A, const char* __restrict__ Bt,
    const float* __restrict__ bias, const float* __restrict__ srow,
    float* __restrict__ Cout, int M, int N, int Kb)
{
  __shared__ char lds[2 * 32768];
  const int tid = threadIdx.x;
  const int lane = tid & 63;
  const int wave = tid >> 6;
  const int wr = wave >> 1;
  const int wc = wave & 1;

  const int nbx = M / 128;
  const int nby = N / 128;
  const int nwg = nbx * nby;
  const int q8 = nwg >> 3, r8 = nwg & 7;
  const int xcd = blockIdx.x & 7, bidx = blockIdx.x >> 3;
  const int wg = (xcd < r8 ? xcd * (q8 + 1) : r8 * (q8 + 1) + (xcd - r8) * q8) + bidx;
  const int r = wg / nby;
  const int c = wg % nby;
  const int row0 = r * 128;
  const int col0 = c * 128;

  const int srw = tid >> 3;
  const int chunk = (tid & 7) ^ (srw & 7);
  const char* Ag = A + (size_t)(row0 + srw) * Kb + chunk * 16;
  const char* Bg = Bt + (size_t)(col0 + srw) * Kb + chunk * 16;
  const int stA = wave * 1024;
  const int stB = 16384 + wave * 1024;

  auto stage = [&](int slot, int h) {
    const int hb = h << 7;
    char* da = lds + slot * 32768 + stA;
    char* db = lds + slot * 32768 + stB;
#pragma unroll
    for (int i = 0; i < 4; ++i)
      stage16(Ag + hb + (size_t)(i * 32) * Kb, da + i * 4096);
#pragma unroll
    for (int i = 0; i < 4; ++i)
      stage16(Bg + hb + (size_t)(i * 32) * Kb, db + i * 4096);
  };

  i32x4 acc[4][4];
#pragma unroll
  for (int i = 0; i < 4; ++i)
#pragma unroll
    for (int j = 0; j < 4; ++j) acc[i][j] = (i32x4)(0);

  const int nS = Kb >> 7;              // 24
  stage(0, 0);
  stage(1, 1);
  asm volatile("s_waitcnt vmcnt(8)" ::: "memory");
  __builtin_amdgcn_s_barrier();

  const int fr = lane & 15;
  const int fg = lane >> 4;
  const int xw = (fg ^ (fr & 7)) << 4;
  const int aoff = (wr * 64 + fr) * 128 + xw;
  const int boff = 16384 + (wc * 64 + fr) * 128 + xw;

  for (int t = 0; t < nS; ++t) {
    const int so = (t & 1) * 32768;
    i32x4 af[2][4], bf[2][4];
#pragma unroll
    for (int h = 0; h < 2; ++h) {
      const int hx = h << 6;
#pragma unroll
      for (int mi = 0; mi < 4; ++mi)
        af[h][mi] = *(const i32x4*)(lds + so + ((aoff ^ hx) + mi * 2048));
#pragma unroll
      for (int ni = 0; ni < 4; ++ni)
        bf[h][ni] = *(const i32x4*)(lds + so + ((boff ^ hx) + ni * 2048));
    }
    asm volatile("s_waitcnt lgkmcnt(0)" ::: "memory");
    __builtin_amdgcn_sched_barrier(0);
    __builtin_amdgcn_s_barrier();
    if (t + 2 < nS) stage(t & 1, t + 2);
    __builtin_amdgcn_s_setprio(1);
#pragma unroll
    for (int h = 0; h < 2; ++h)
#pragma unroll
      for (int mi = 0; mi < 4; ++mi)
#pragma unroll
        for (int ni = 0; ni < 4; ++ni)
          acc[mi][ni] = __builtin_amdgcn_mfma_i32_16x16x64_i8(
              af[h][mi], bf[h][ni], acc[mi][ni], 0, 0, 0);
    __builtin_amdgcn_s_setprio(0);
    if (t + 2 < nS) asm volatile("s_waitcnt vmcnt(8)" ::: "memory");
    else            asm volatile("s_waitcnt vmcnt(0)" ::: "memory");
    __builtin_amdgcn_s_barrier();
  }

  const int orow = row0 + wr * 64 + fg * 4;
  const int ocol = col0 + wc * 64 + fr;
#pragma unroll
  for (int mi = 0; mi < 4; ++mi) {
    float sr[4];
#pragma unroll
    for (int rg = 0; rg < 4; ++rg) sr[rg] = srow[orow + mi * 16 + rg];
#pragma unroll
    for (int ni = 0; ni < 4; ++ni) {
      const int col = ocol + ni * 16;
      const float bv = bias[col];
#pragma unroll
      for (int rg = 0; rg < 4; ++rg) {
        float v = sr[rg] * (float)acc[mi][ni][rg] + bv;
        Cout[(size_t)(orow + mi * 16 + rg) * N + col] = fmaxf(v, 0.f);
      }
    }
  }
}

// ---------------- launch ----------------

extern "C" void kernel_launch(void* const* d_in, const int* in_sizes, int n_in,
                              void* d_out, int out_size, void* d_ws, size_t ws_size,
                              hipStream_t stream) {
  const float* x  = (const float*)d_in[0];
  const float* w1 = (const float*)d_in[1];
  const float* b1 = (const float*)d_in[2];
  const float* w2 = (const float*)d_in[3];
  const float* b2 = (const float*)d_in[4];
  const float* as = (const float*)d_in[5];

  const int Mrows = 64 * 196;   // 12544
  const int D = 768, H = 3072;

  char* ws = (char*)d_ws;
  size_t off = 0;
  auto align256 = [](size_t v) { return (v + 255) & ~(size_t)255; };
  unsigned* mx = (unsigned*)(ws + off); off += 256;
  char* xq8    = (char*)(ws + off);     off += align256((size_t)Mrows * D);
  char* w1q8   = (char*)(ws + off);     off += align256((size_t)H * D);
  char* w2q8   = (char*)(ws + off);     off += align256((size_t)D * H);
  float* b1i = (float*)(ws + off); off += align256((size_t)H * 4);
  float* b2i = (float*)(ws + off); off += align256((size_t)D * 4);
  float* stab = (float*)(ws + off); off += align256((size_t)Mrows * 24 * 4);
  float* srow = (float*)(ws + off); off += align256((size_t)Mrows * 4);
  unsigned char* hq  = (unsigned char*)(ws + off); off += align256((size_t)Mrows * H);
  unsigned char* hq2 = (unsigned char*)(ws + off); off += align256((size_t)Mrows * H);
  if (off > ws_size) return;

  float* out = (float*)d_out;
  float* s_out = out + (out_size - 1);

  hipMemsetAsync(mx, 0, 8, stream);

  const int nw4 = H * D / 4;
  prep_kernel<<<dim3(1024, 3), dim3(256), 0, stream>>>(
      (const float4*)x, (uchar4*)xq8, Mrows * D / 4,
      (const float4*)w1, (const float4*)w2, nw4, mx);
  quantwb_kernel<<<dim3(1024, 3), dim3(256), 0, stream>>>(
      (const float4*)w1, (const float4*)w2, (uchar4*)w1q8, (uchar4*)w2q8,
      b1, b2, b1i, b2i, mx, as, s_out, nw4, H, D);

  // fc1: int8 128x128, 98*24 = 2352 blocks, Kb = 768
  gemm_fc1<<<dim3((Mrows / 128) * (H / 128)), dim3(256), 0, stream>>>(
      xq8, w1q8, b1i, hq, stab, Mrows, H, D);
  // requant: per-chunk -> per-row scales, 4 rows/block
  requant_kernel<<<dim3(Mrows / 4), dim3(256), 0, stream>>>(
      (const uint4*)hq, (uint4*)hq2, stab, srow, Mrows);
  // fc2: pure int8 128x128, 588 blocks, Kb = 3072
  gemm_fc2<<<dim3((Mrows / 128) * (D / 128)), dim3(256), 0, stream>>>(
      (const char*)hq2, w2q8, b2i, srow, out, Mrows, D, H);
}

// Round 12
// 147.158 us; speedup vs baseline: 1.2893x; 1.0118x over previous
//
#include <hip/hip_runtime.h>
#include <hip/hip_bf16.h>
#include <type_traits>

typedef __attribute__((ext_vector_type(4))) float f32x4;
typedef __attribute__((ext_vector_type(4))) int   i32x4;

static __device__ __forceinline__ void stage16(const void* g, void* l) {
  __builtin_amdgcn_global_load_lds((const __attribute__((address_space(1))) void*)g,
                                   (__attribute__((address_space(3))) void*)l,
                                   16, 0, 0);
}

// ---------------- prep ----------------
// y==0 (1024 blocks): x f32 -> int8. y==1/2 (96 blocks): maxabs(w1/w2).
__global__ void prep_kernel(const float4* __restrict__ x, uchar4* __restrict__ xq, int n4x,
                            const float4* __restrict__ w1, const float4* __restrict__ w2,
                            int n4w, unsigned* __restrict__ mx) {
  if (blockIdx.y == 0) {
    const int stride = gridDim.x * blockDim.x;
    for (int i = blockIdx.x * blockDim.x + threadIdx.x; i < n4x; i += stride) {
      float4 v = x[i];
      uchar4 o;
      o.x = (unsigned char)(char)fminf(fmaxf(v.x, -127.f), 127.f);
      o.y = (unsigned char)(char)fminf(fmaxf(v.y, -127.f), 127.f);
      o.z = (unsigned char)(char)fminf(fmaxf(v.z, -127.f), 127.f);
      o.w = (unsigned char)(char)fminf(fmaxf(v.w, -127.f), 127.f);
      xq[i] = o;
    }
  } else {
    if (blockIdx.x >= 96) return;
    __shared__ unsigned red[4];
    const float4* w = (blockIdx.y == 1) ? w1 : w2;
    unsigned m = 0;
    const int stride = 96 * 256;
    for (int i = blockIdx.x * blockDim.x + threadIdx.x; i < n4w; i += stride) {
      float4 v = w[i];
      unsigned a;
      a = __float_as_uint(fabsf(v.x)); m = m > a ? m : a;
      a = __float_as_uint(fabsf(v.y)); m = m > a ? m : a;
      a = __float_as_uint(fabsf(v.z)); m = m > a ? m : a;
      a = __float_as_uint(fabsf(v.w)); m = m > a ? m : a;
    }
#pragma unroll
    for (int off = 32; off > 0; off >>= 1) {
      unsigned t = (unsigned)__shfl_down((int)m, off, 64);
      m = m > t ? m : t;
    }
    if ((threadIdx.x & 63) == 0) red[threadIdx.x >> 6] = m;
    __syncthreads();
    if (threadIdx.x == 0) {
      unsigned t0 = red[0] > red[1] ? red[0] : red[1];
      unsigned t1 = red[2] > red[3] ? red[2] : red[3];
      atomicMax(mx + blockIdx.y - 1, t0 > t1 ? t0 : t1);
    }
  }
}

// y==0: w1 -> int8 (linear) ; y==1: w2 -> int8 with k permuted by pi within each
// 64-k group (byte p=4*dl+i holds k=dl+16*i) ; y==2 blk0: biases + final scale.
__global__ void quantwb_kernel(const float* __restrict__ w1, const float* __restrict__ w2,
                               unsigned char* __restrict__ w1q, unsigned* __restrict__ w2qw,
                               const float* __restrict__ b1, const float* __restrict__ b2,
                               float* __restrict__ b1i, float* __restrict__ b2i,
                               const unsigned* __restrict__ mx, const float* __restrict__ a_s,
                               float* __restrict__ s_out, int n4, int H, int D) {
  const float ws1 = __uint_as_float(mx[0]) / 127.0f;
  const float ws2 = __uint_as_float(mx[1]) / 127.0f;
  const int stride = gridDim.x * blockDim.x;
  if (blockIdx.y == 0) {
    const float4* w = (const float4*)w1;
    uchar4* wq = (uchar4*)w1q;
    for (int i = blockIdx.x * blockDim.x + threadIdx.x; i < n4; i += stride) {
      float4 v = w[i];
      uchar4 o;
      o.x = (unsigned char)(char)fminf(fmaxf(rintf(v.x / ws1), -127.f), 127.f);
      o.y = (unsigned char)(char)fminf(fmaxf(rintf(v.y / ws1), -127.f), 127.f);
      o.z = (unsigned char)(char)fminf(fmaxf(rintf(v.z / ws1), -127.f), 127.f);
      o.w = (unsigned char)(char)fminf(fmaxf(rintf(v.w / ws1), -127.f), 127.f);
      wq[i] = o;
    }
  } else if (blockIdx.y == 1) {
    // one output dword per iter: row n, dword d; group=d>>4, dl=d&15; k = grp*64+dl+16i
    const int ndw = n4;                       // D*H/4 dwords total
    const int dpr = H >> 2;                   // dwords per row (768)
    for (int g = blockIdx.x * blockDim.x + threadIdx.x; g < ndw; g += stride) {
      const int n = g / dpr;
      const int d = g - n * dpr;
      const int grp = d >> 4, dl = d & 15;
      const float* src = w2 + (size_t)n * H + grp * 64 + dl;
      unsigned r = 0;
#pragma unroll
      for (int i = 0; i < 4; ++i) {
        float v = src[i * 16];
        int q = (int)fminf(fmaxf(rintf(v / ws2), -127.f), 127.f);
        r |= ((unsigned)q & 0xFFu) << (i * 8);
      }
      w2qw[g] = r;
    }
  } else {
    if (blockIdx.x != 0) return;
    const float s0 = a_s[0];
    const float s1 = s0 * ws1;
    const float d1 = ws1 * s0;
    const float d2 = ws2 * s1;
    if (threadIdx.x == 0) s_out[0] = s1 * ws2;
    for (int i = threadIdx.x; i < H; i += blockDim.x) {
      float q = rintf(b1[i] / d1);
      b1i[i] = fminf(fmaxf(q, -2147483647.f), 2147483647.f);
    }
    for (int i = threadIdx.x; i < D; i += blockDim.x) {
      float q = rintf(b2[i] / d2);
      b2i[i] = fminf(fmaxf(q, -2147483647.f), 2147483647.f);
    }
  }
}

// ---------------- fc1: 128x128 int8 GEMM, 4 waves, 2-slot BK=128B ----------------
// Epilogue: per-row-chunk (128 cols) quant; each lane packs its 4 nf-bytes into one
// dword stored at pi-permuted position (p = 4*fr + nf <-> col = fr + 16*nf). h_q is
// thus stored k-permuted within 64-col groups; w2q carries the SAME permutation, so
// fc2's dot products are invariant. No LDS staging, no bank conflicts, coalesced.

__global__ __launch_bounds__(256) void gemm_fc1(
    const char* __restrict__ A, const char* __restrict__ Bt,
    const float* __restrict__ b1f, unsigned char* __restrict__ hq,
    float* __restrict__ stab, int M, int N, int Kb)
{
  __shared__ char lds[2 * 32768];
  const int tid = threadIdx.x;
  const int lane = tid & 63;
  const int wave = tid >> 6;
  const int wr = wave >> 1;
  const int wc = wave & 1;

  // 16-row-tile bands, col-major within band (A-band ~1.5MB L2-resident)
  const int nbx = M / 128;             // 98
  const int nby = N / 128;             // 24
  const int bandSize = 16 * nby;
  const int b = blockIdx.x / bandSize;
  const int local = blockIdx.x - b * bandSize;
  const int r0 = b * 16;
  const int rn = min(16, nbx - r0);
  const int c = local / rn;
  const int r = r0 + (local - c * rn);
  const int row0 = r * 128;
  const int col0 = c * 128;

  const int srw = tid >> 3;
  const int chunk = (tid & 7) ^ (srw & 7);
  const char* Ag = A + (size_t)(row0 + srw) * Kb + chunk * 16;
  const char* Bg = Bt + (size_t)(col0 + srw) * Kb + chunk * 16;
  const int stA = wave * 1024;
  const int stB = 16384 + wave * 1024;

  auto stage = [&](int slot, int h) {
    const int hb = h << 7;
    char* da = lds + slot * 32768 + stA;
    char* db = lds + slot * 32768 + stB;
#pragma unroll
    for (int i = 0; i < 4; ++i)
      stage16(Ag + hb + (size_t)(i * 32) * Kb, da + i * 4096);
#pragma unroll
    for (int i = 0; i < 4; ++i)
      stage16(Bg + hb + (size_t)(i * 32) * Kb, db + i * 4096);
  };

  i32x4 acc[4][4];
#pragma unroll
  for (int i = 0; i < 4; ++i)
#pragma unroll
    for (int j = 0; j < 4; ++j) acc[i][j] = (i32x4)(0);

  const int nS = Kb >> 7;              // 6
  stage(0, 0);
  stage(1, 1);
  asm volatile("s_waitcnt vmcnt(8)" ::: "memory");
  __builtin_amdgcn_s_barrier();

  const int fr = lane & 15;
  const int fg = lane >> 4;
  const int xw = (fg ^ (fr & 7)) << 4;
  const int aoff = (wr * 64 + fr) * 128 + xw;
  const int boff = 16384 + (wc * 64 + fr) * 128 + xw;

  for (int t = 0; t < nS; ++t) {
    const int so = (t & 1) * 32768;
    i32x4 af[2][4], bf[2][4];
#pragma unroll
    for (int h = 0; h < 2; ++h) {
      const int hx = h << 6;
#pragma unroll
      for (int mi = 0; mi < 4; ++mi)
        af[h][mi] = *(const i32x4*)(lds + so + ((aoff ^ hx) + mi * 2048));
#pragma unroll
      for (int ni = 0; ni < 4; ++ni)
        bf[h][ni] = *(const i32x4*)(lds + so + ((boff ^ hx) + ni * 2048));
    }
    asm volatile("s_waitcnt lgkmcnt(0)" ::: "memory");
    __builtin_amdgcn_sched_barrier(0);
    __builtin_amdgcn_s_barrier();
    if (t + 2 < nS) stage(t & 1, t + 2);
    __builtin_amdgcn_s_setprio(1);
#pragma unroll
    for (int h = 0; h < 2; ++h)
#pragma unroll
      for (int mi = 0; mi < 4; ++mi)
#pragma unroll
        for (int ni = 0; ni < 4; ++ni)
          acc[mi][ni] = __builtin_amdgcn_mfma_i32_16x16x64_i8(
              af[h][mi], bf[h][ni], acc[mi][ni], 0, 0, 0);
    __builtin_amdgcn_s_setprio(0);
    if (t + 2 < nS) asm volatile("s_waitcnt vmcnt(8)" ::: "memory");
    else            asm volatile("s_waitcnt vmcnt(0)" ::: "memory");
    __builtin_amdgcn_s_barrier();
  }

  // ---- epilogue: per-row-chunk quant, pi-packed coalesced dword stores ----
  __syncthreads();
  float* rowtab = (float*)lds;                 // [128][2], slot0 reuse
  const int orow_l = wr * 64 + fg * 4;
  const int ocol_l = wc * 64 + fr;
  float bv[4];
#pragma unroll
  for (int nf = 0; nf < 4; ++nf) bv[nf] = b1f[col0 + ocol_l + nf * 16];

  // phase 1: per-row max over this tile (reduce across fr lanes)
#pragma unroll
  for (int mf = 0; mf < 4; ++mf) {
    float rmax[4] = {0.f, 0.f, 0.f, 0.f};
#pragma unroll
    for (int nf = 0; nf < 4; ++nf)
#pragma unroll
      for (int rg = 0; rg < 4; ++rg) {
        float v = (float)acc[mf][nf][rg] + bv[nf];
        rmax[rg] = fmaxf(rmax[rg], fabsf(v));
      }
#pragma unroll
    for (int rg = 0; rg < 4; ++rg) {
#pragma unroll
      for (int m = 1; m <= 8; m <<= 1)
        rmax[rg] = fmaxf(rmax[rg], __shfl_xor(rmax[rg], m, 64));
      if (fr == 0) rowtab[(orow_l + mf * 16 + rg) * 2 + wc] = rmax[rg];
    }
  }
  __syncthreads();
  // phase 2: quantize + pack 4 bytes -> one dword store (p = 4*fr + nf)
#pragma unroll
  for (int mf = 0; mf < 4; ++mf) {
#pragma unroll
    for (int rg = 0; rg < 4; ++rg) {
      const int lr = orow_l + mf * 16 + rg;
      float rm = fmaxf(rowtab[lr * 2], rowtab[lr * 2 + 1]);
      float inv = rm > 0.f ? 127.f / rm : 0.f;
      if (wc == 0 && fr == 0) stab[(size_t)(row0 + lr) * 24 + c] = rm * (1.f / 127.f);
      unsigned pk = 0;
#pragma unroll
      for (int nf = 0; nf < 4; ++nf) {
        float v = (float)acc[mf][nf][rg] + bv[nf];
        int q = (int)rintf(v * inv);
        pk |= ((unsigned)q & 0xFFu) << (nf * 8);
      }
      *(unsigned*)(hq + (size_t)(row0 + lr) * N + col0 + wc * 64 + fr * 4) = pk;
    }
  }
}

// ---------------- requant: per-chunk h_q -> per-row h_q' + srow ----------------
// 4 rows/block. Byte chunk-ids are pi-invariant (pi permutes within 64 < 128).
__global__ void requant_kernel(const uint4* __restrict__ hq, uint4* __restrict__ hq2,
                               const float* __restrict__ stab, float* __restrict__ srow,
                               int Mrows) {
  const int row = blockIdx.x * 4 + (threadIdx.x >> 6);
  if (row >= Mrows) return;
  const int lane = threadIdx.x & 63;
  const float* st = stab + (size_t)row * 24;
  float sr = 0.f;
#pragma unroll
  for (int i = 0; i < 24; ++i) sr = fmaxf(sr, st[i]);
  if (lane == 0) srow[row] = sr;
  const float rinv = sr > 0.f ? 1.f / sr : 0.f;
  const uint4* in = hq + (size_t)row * 192;
  uint4* outp = hq2 + (size_t)row * 192;
#pragma unroll
  for (int it = 0; it < 3; ++it) {
    const int j = lane + it * 64;
    const float ratio = st[j >> 3] * rinv;
    uint4 iv = in[j], ov;
    unsigned* ip = (unsigned*)&iv;
    unsigned* op = (unsigned*)&ov;
#pragma unroll
    for (int w = 0; w < 4; ++w) {
      unsigned rr = 0;
#pragma unroll
      for (int k = 0; k < 4; ++k) {
        int q = (int)(signed char)((ip[w] >> (k * 8)) & 0xFF);
        int nq = (int)rintf((float)q * ratio);
        rr |= ((unsigned)nq & 0xFF) << (k * 8);
      }
      op[w] = rr;
    }
    outp[j] = ov;
  }
}

// ---------------- fc2: 128x128 pure int8 GEMM (proven loop, unchanged) ----------------
__global__ __launch_bounds__(256) void gemm_fc2(
    const char* __restrict__ A, const char* __restrict__ Bt,
    const float* __restrict__ bias, const float* __restrict__ srow,
    float* __restrict__ Cout, int M, int N, int Kb)
{
  __shared__ char lds[2 * 32768];
  const int tid = threadIdx.x;
  const int lane = tid & 63;
  const int wave = tid >> 6;
  const int wr = wave >> 1;
  const int wc = wave & 1;

  const int nbx = M / 128;
  const int nby = N / 128;
  const int nwg = nbx * nby;
  const int q8 = nwg >> 3, r8 = nwg & 7;
  const int xcd = blockIdx.x & 7, bidx = blockIdx.x >> 3;
  const int wg = (xcd < r8 ? xcd * (q8 + 1) : r8 * (q8 + 1) + (xcd - r8) * q8) + bidx;
  const int r = wg / nby;
  const int c = wg % nby;
  const int row0 = r * 128;
  const int col0 = c * 128;

  const int srw = tid >> 3;
  const int chunk = (tid & 7) ^ (srw & 7);
  const char* Ag = A + (size_t)(row0 + srw) * Kb + chunk * 16;
  const char* Bg = Bt + (size_t)(col0 + srw) * Kb + chunk * 16;
  const int stA = wave * 1024;
  const int stB = 16384 + wave * 1024;

  auto stage = [&](int slot, int h) {
    const int hb = h << 7;
    char* da = lds + slot * 32768 + stA;
    char* db = lds + slot * 32768 + stB;
#pragma unroll
    for (int i = 0; i < 4; ++i)
      stage16(Ag + hb + (size_t)(i * 32) * Kb, da + i * 4096);
#pragma unroll
    for (int i = 0; i < 4; ++i)
      stage16(Bg + hb + (size_t)(i * 32) * Kb, db + i * 4096);
  };

  i32x4 acc[4][4];
#pragma unroll
  for (int i = 0; i < 4; ++i)
#pragma unroll
    for (int j = 0; j < 4; ++j) acc[i][j] = (i32x4)(0);

  const int nS = Kb >> 7;              // 24
  stage(0, 0);
  stage(1, 1);
  asm volatile("s_waitcnt vmcnt(8)" ::: "memory");
  __builtin_amdgcn_s_barrier();

  const int fr = lane & 15;
  const int fg = lane >> 4;
  const int xw = (fg ^ (fr & 7)) << 4;
  const int aoff = (wr * 64 + fr) * 128 + xw;
  const int boff = 16384 + (wc * 64 + fr) * 128 + xw;

  for (int t = 0; t < nS; ++t) {
    const int so = (t & 1) * 32768;
    i32x4 af[2][4], bf[2][4];
#pragma unroll
    for (int h = 0; h < 2; ++h) {
      const int hx = h << 6;
#pragma unroll
      for (int mi = 0; mi < 4; ++mi)
        af[h][mi] = *(const i32x4*)(lds + so + ((aoff ^ hx) + mi * 2048));
#pragma unroll
      for (int ni = 0; ni < 4; ++ni)
        bf[h][ni] = *(const i32x4*)(lds + so + ((boff ^ hx) + ni * 2048));
    }
    asm volatile("s_waitcnt lgkmcnt(0)" ::: "memory");
    __builtin_amdgcn_sched_barrier(0);
    __builtin_amdgcn_s_barrier();
    if (t + 2 < nS) stage(t & 1, t + 2);
    __builtin_amdgcn_s_setprio(1);
#pragma unroll
    for (int h = 0; h < 2; ++h)
#pragma unroll
      for (int mi = 0; mi < 4; ++mi)
#pragma unroll
        for (int ni = 0; ni < 4; ++ni)
          acc[mi][ni] = __builtin_amdgcn_mfma_i32_16x16x64_i8(
              af[h][mi], bf[h][ni], acc[mi][ni], 0, 0, 0);
    __builtin_amdgcn_s_setprio(0);
    if (t + 2 < nS) asm volatile("s_waitcnt vmcnt(8)" ::: "memory");
    else            asm volatile("s_waitcnt vmcnt(0)" ::: "memory");
    __builtin_amdgcn_s_barrier();
  }

  const int orow = row0 + wr * 64 + fg * 4;
  const int ocol = col0 + wc * 64 + fr;
#pragma unroll
  for (int mi = 0; mi < 4; ++mi) {
    float sr[4];
#pragma unroll
    for (int rg = 0; rg < 4; ++rg) sr[rg] = srow[orow + mi * 16 + rg];
#pragma unroll
    for (int ni = 0; ni < 4; ++ni) {
      const int col = ocol + ni * 16;
      const float bv = bias[col];
#pragma unroll
      for (int rg = 0; rg < 4; ++rg) {
        float v = sr[rg] * (float)acc[mi][ni][rg] + bv;
        Cout[(size_t)(orow + mi * 16 + rg) * N + col] = fmaxf(v, 0.f);
      }
    }
  }
}

// ---------------- launch ----------------

extern "C" void kernel_launch(void* const* d_in, const int* in_sizes, int n_in,
                              void* d_out, int out_size, void* d_ws, size_t ws_size,
                              hipStream_t stream) {
  const float* x  = (const float*)d_in[0];
  const float* w1 = (const float*)d_in[1];
  const float* b1 = (const float*)d_in[2];
  const float* w2 = (const float*)d_in[3];
  const float* b2 = (const float*)d_in[4];
  const float* as = (const float*)d_in[5];

  const int Mrows = 64 * 196;   // 12544
  const int D = 768, H = 3072;

  char* ws = (char*)d_ws;
  size_t off = 0;
  auto align256 = [](size_t v) { return (v + 255) & ~(size_t)255; };
  unsigned* mx = (unsigned*)(ws + off); off += 256;
  char* xq8    = (char*)(ws + off);     off += align256((size_t)Mrows * D);
  char* w1q8   = (char*)(ws + off);     off += align256((size_t)H * D);
  char* w2q8   = (char*)(ws + off);     off += align256((size_t)D * H);
  float* b1i = (float*)(ws + off); off += align256((size_t)H * 4);
  float* b2i = (float*)(ws + off); off += align256((size_t)D * 4);
  float* stab = (float*)(ws + off); off += align256((size_t)Mrows * 24 * 4);
  float* srow = (float*)(ws + off); off += align256((size_t)Mrows * 4);
  unsigned char* hq  = (unsigned char*)(ws + off); off += align256((size_t)Mrows * H);
  unsigned char* hq2 = (unsigned char*)(ws + off); off += align256((size_t)Mrows * H);
  if (off > ws_size) return;

  float* out = (float*)d_out;
  float* s_out = out + (out_size - 1);

  hipMemsetAsync(mx, 0, 8, stream);

  const int nw4 = H * D / 4;
  prep_kernel<<<dim3(1024, 3), dim3(256), 0, stream>>>(
      (const float4*)x, (uchar4*)xq8, Mrows * D / 4,
      (const float4*)w1, (const float4*)w2, nw4, mx);
  quantwb_kernel<<<dim3(1024, 3), dim3(256), 0, stream>>>(
      w1, w2, (unsigned char*)w1q8, (unsigned*)w2q8,
      b1, b2, b1i, b2i, mx, as, s_out, nw4, H, D);

  // fc1: int8 128x128, 98*24 = 2352 blocks, Kb = 768
  gemm_fc1<<<dim3((Mrows / 128) * (H / 128)), dim3(256), 0, stream>>>(
      xq8, w1q8, b1i, hq, stab, Mrows, H, D);
  // requant: per-chunk -> per-row scales, 4 rows/block
  requant_kernel<<<dim3(Mrows / 4), dim3(256), 0, stream>>>(
      (const uint4*)hq, (uint4*)hq2, stab, srow, Mrows);
  // fc2: pure int8 128x128, 588 blocks, Kb = 3072
  gemm_fc2<<<dim3((Mrows / 128) * (D / 128)), dim3(256), 0, stream>>>(
      (const char*)hq2, w2q8, b2i, srow, out, Mrows, D, H);
}

// Round 13
// 143.860 us; speedup vs baseline: 1.3189x; 1.0229x over previous
//
#include <hip/hip_runtime.h>
#include <hip/hip_bf16.h>
#include <type_traits>

typedef __attribute__((ext_vector_type(4))) float f32x4;
typedef __attribute__((ext_vector_type(4))) int   i32x4;

static __device__ __forceinline__ void stage16(const void* g, void* l) {
  __builtin_amdgcn_global_load_lds((const __attribute__((address_space(1))) void*)g,
                                   (__attribute__((address_space(3))) void*)l,
                                   16, 0, 0);
}

// ---------------- prep: maxabs(w1/w2) only ----------------
__global__ void prep_kernel(const float4* __restrict__ w1, const float4* __restrict__ w2,
                            int n4w, unsigned* __restrict__ mx) {
  __shared__ unsigned red[4];
  const float4* w = blockIdx.y ? w2 : w1;
  unsigned m = 0;
  const int stride = gridDim.x * blockDim.x;
  for (int i = blockIdx.x * blockDim.x + threadIdx.x; i < n4w; i += stride) {
    float4 v = w[i];
    unsigned a;
    a = __float_as_uint(fabsf(v.x)); m = m > a ? m : a;
    a = __float_as_uint(fabsf(v.y)); m = m > a ? m : a;
    a = __float_as_uint(fabsf(v.z)); m = m > a ? m : a;
    a = __float_as_uint(fabsf(v.w)); m = m > a ? m : a;
  }
#pragma unroll
  for (int off = 32; off > 0; off >>= 1) {
    unsigned t = (unsigned)__shfl_down((int)m, off, 64);
    m = m > t ? m : t;
  }
  if ((threadIdx.x & 63) == 0) red[threadIdx.x >> 6] = m;
  __syncthreads();
  if (threadIdx.x == 0) {
    unsigned t0 = red[0] > red[1] ? red[0] : red[1];
    unsigned t1 = red[2] > red[3] ? red[2] : red[3];
    atomicMax(mx + blockIdx.y, t0 > t1 ? t0 : t1);
  }
}

// y==0: w1 -> int8 (linear) ; y==1: w2 -> int8 pi-permuted within 64-k groups
// (byte p=4*dl+i holds k=dl+16*i) ; y==2: x -> int8 ; y==3 blk0: biases + scale.
__global__ void quantwb_kernel(const float* __restrict__ w1, const float* __restrict__ w2,
                               unsigned char* __restrict__ w1q, unsigned* __restrict__ w2qw,
                               const float4* __restrict__ x, uchar4* __restrict__ xq, int n4x,
                               const float* __restrict__ b1, const float* __restrict__ b2,
                               float* __restrict__ b1i, float* __restrict__ b2i,
                               const unsigned* __restrict__ mx, const float* __restrict__ a_s,
                               float* __restrict__ s_out, int n4, int H, int D) {
  const float ws1 = __uint_as_float(mx[0]) / 127.0f;
  const float ws2 = __uint_as_float(mx[1]) / 127.0f;
  const int stride = gridDim.x * blockDim.x;
  if (blockIdx.y == 0) {
    const float4* w = (const float4*)w1;
    uchar4* wq = (uchar4*)w1q;
    for (int i = blockIdx.x * blockDim.x + threadIdx.x; i < n4; i += stride) {
      float4 v = w[i];
      uchar4 o;
      o.x = (unsigned char)(char)fminf(fmaxf(rintf(v.x / ws1), -127.f), 127.f);
      o.y = (unsigned char)(char)fminf(fmaxf(rintf(v.y / ws1), -127.f), 127.f);
      o.z = (unsigned char)(char)fminf(fmaxf(rintf(v.z / ws1), -127.f), 127.f);
      o.w = (unsigned char)(char)fminf(fmaxf(rintf(v.w / ws1), -127.f), 127.f);
      wq[i] = o;
    }
  } else if (blockIdx.y == 1) {
    const int ndw = n4;                       // D*H/4 dwords
    const int dpr = H >> 2;                   // dwords per row (768)
    for (int g = blockIdx.x * blockDim.x + threadIdx.x; g < ndw; g += stride) {
      const int n = g / dpr;
      const int d = g - n * dpr;
      const int grp = d >> 4, dl = d & 15;
      const float* src = w2 + (size_t)n * H + grp * 64 + dl;
      unsigned r = 0;
#pragma unroll
      for (int i = 0; i < 4; ++i) {
        float v = src[i * 16];
        int q = (int)fminf(fmaxf(rintf(v / ws2), -127.f), 127.f);
        r |= ((unsigned)q & 0xFFu) << (i * 8);
      }
      w2qw[g] = r;
    }
  } else if (blockIdx.y == 2) {
    for (int i = blockIdx.x * blockDim.x + threadIdx.x; i < n4x; i += stride) {
      float4 v = x[i];
      uchar4 o;
      o.x = (unsigned char)(char)fminf(fmaxf(v.x, -127.f), 127.f);
      o.y = (unsigned char)(char)fminf(fmaxf(v.y, -127.f), 127.f);
      o.z = (unsigned char)(char)fminf(fmaxf(v.z, -127.f), 127.f);
      o.w = (unsigned char)(char)fminf(fmaxf(v.w, -127.f), 127.f);
      xq[i] = o;
    }
  } else {
    if (blockIdx.x != 0) return;
    const float s0 = a_s[0];
    const float s1 = s0 * ws1;
    const float d1 = ws1 * s0;
    const float d2 = ws2 * s1;
    if (threadIdx.x == 0) s_out[0] = s1 * ws2;
    for (int i = threadIdx.x; i < H; i += blockDim.x) {
      float q = rintf(b1[i] / d1);
      b1i[i] = fminf(fmaxf(q, -2147483647.f), 2147483647.f);
    }
    for (int i = threadIdx.x; i < D; i += blockDim.x) {
      float q = rintf(b2[i] / d2);
      b2i[i] = fminf(fmaxf(q, -2147483647.f), 2147483647.f);
    }
  }
}

// ---------------- fc1: 128x128 int8, SINGLE-buffer 32KB, 5 blocks/CU ----------------
// m97 2-barrier structure: stage -> sync -> 32 MFMA -> sync. At Kb=768 (6 steps)
// the per-step drain overlaps across 5 resident blocks (occupancy > pipelining
// at short K — R8/R11 double-buffer at 2 blocks/CU measured slower).
// Epilogue: per-row-chunk quant, pi-packed dword stores (R12, conflict-free).

__global__ __launch_bounds__(256) void gemm_fc1(
    const char* __restrict__ A, const char* __restrict__ Bt,
    const float* __restrict__ b1f, unsigned char* __restrict__ hq,
    float* __restrict__ stab, int M, int N, int Kb)
{
  __shared__ char lds[32768 + 1024];   // As 16KB | Bs 16KB | rowtab 1KB
  const int tid = threadIdx.x;
  const int lane = tid & 63;
  const int wave = tid >> 6;
  const int wr = wave >> 1;
  const int wc = wave & 1;

  // 16-row-tile bands, col-major within band (A-band ~1.5MB L2-resident)
  const int nbx = M / 128;             // 98
  const int nby = N / 128;             // 24
  const int bandSize = 16 * nby;
  const int b = blockIdx.x / bandSize;
  const int local = blockIdx.x - b * bandSize;
  const int r0 = b * 16;
  const int rn = min(16, nbx - r0);
  const int c = local / rn;
  const int r = r0 + (local - c * rn);
  const int row0 = r * 128;
  const int col0 = c * 128;

  const int srw = tid >> 3;
  const int chunk = (tid & 7) ^ (srw & 7);
  const char* Ag = A + (size_t)(row0 + srw) * Kb + chunk * 16;
  const char* Bg = Bt + (size_t)(col0 + srw) * Kb + chunk * 16;
  char* const stAp = lds + wave * 1024;
  char* const stBp = lds + 16384 + wave * 1024;

  i32x4 acc[4][4];
#pragma unroll
  for (int i = 0; i < 4; ++i)
#pragma unroll
    for (int j = 0; j < 4; ++j) acc[i][j] = (i32x4)(0);

  // hoist bias loads (overlap with K-loop)
  const int fr = lane & 15;
  const int fg = lane >> 4;
  const int ocol_l = wc * 64 + fr;
  float bv[4];
#pragma unroll
  for (int nf = 0; nf < 4; ++nf) bv[nf] = b1f[col0 + ocol_l + nf * 16];

  const int xw = (fg ^ (fr & 7)) << 4;
  const int aoff = (wr * 64 + fr) * 128 + xw;
  const int boff = 16384 + (wc * 64 + fr) * 128 + xw;

  const int nS = Kb >> 7;              // 6
  for (int t = 0; t < nS; ++t) {
    const int hb = t << 7;
#pragma unroll
    for (int i = 0; i < 4; ++i)
      stage16(Ag + hb + (size_t)(i * 32) * Kb, stAp + i * 4096);
#pragma unroll
    for (int i = 0; i < 4; ++i)
      stage16(Bg + hb + (size_t)(i * 32) * Kb, stBp + i * 4096);
    __syncthreads();                   // vmcnt(0) drain + barrier: LDS ready
    i32x4 af[2][4], bf[2][4];
#pragma unroll
    for (int h = 0; h < 2; ++h) {
      const int hx = h << 6;
#pragma unroll
      for (int mi = 0; mi < 4; ++mi)
        af[h][mi] = *(const i32x4*)(lds + ((aoff ^ hx) + mi * 2048));
#pragma unroll
      for (int ni = 0; ni < 4; ++ni)
        bf[h][ni] = *(const i32x4*)(lds + ((boff ^ hx) + ni * 2048));
    }
    __builtin_amdgcn_s_setprio(1);
#pragma unroll
    for (int h = 0; h < 2; ++h)
#pragma unroll
      for (int mi = 0; mi < 4; ++mi)
#pragma unroll
        for (int ni = 0; ni < 4; ++ni)
          acc[mi][ni] = __builtin_amdgcn_mfma_i32_16x16x64_i8(
              af[h][mi], bf[h][ni], acc[mi][ni], 0, 0, 0);
    __builtin_amdgcn_s_setprio(0);
    __syncthreads();                   // all waves' reads done -> safe overwrite
  }

  // ---- epilogue: per-row-chunk quant, pi-packed coalesced dword stores ----
  float* rowtab = (float*)(lds + 32768);       // [128][2]
  const int orow_l = wr * 64 + fg * 4;

#pragma unroll
  for (int mf = 0; mf < 4; ++mf) {
    float rmax[4] = {0.f, 0.f, 0.f, 0.f};
#pragma unroll
    for (int nf = 0; nf < 4; ++nf)
#pragma unroll
      for (int rg = 0; rg < 4; ++rg) {
        float v = (float)acc[mf][nf][rg] + bv[nf];
        rmax[rg] = fmaxf(rmax[rg], fabsf(v));
      }
#pragma unroll
    for (int rg = 0; rg < 4; ++rg) {
#pragma unroll
      for (int m = 1; m <= 8; m <<= 1)
        rmax[rg] = fmaxf(rmax[rg], __shfl_xor(rmax[rg], m, 64));
      if (fr == 0) rowtab[(orow_l + mf * 16 + rg) * 2 + wc] = rmax[rg];
    }
  }
  __syncthreads();
#pragma unroll
  for (int mf = 0; mf < 4; ++mf) {
#pragma unroll
    for (int rg = 0; rg < 4; ++rg) {
      const int lr = orow_l + mf * 16 + rg;
      float rm = fmaxf(rowtab[lr * 2], rowtab[lr * 2 + 1]);
      float inv = rm > 0.f ? 127.f / rm : 0.f;
      if (wc == 0 && fr == 0) stab[(size_t)(row0 + lr) * 24 + c] = rm * (1.f / 127.f);
      unsigned pk = 0;
#pragma unroll
      for (int nf = 0; nf < 4; ++nf) {
        float v = (float)acc[mf][nf][rg] + bv[nf];
        int q = (int)rintf(v * inv);
        pk |= ((unsigned)q & 0xFFu) << (nf * 8);
      }
      *(unsigned*)(hq + (size_t)(row0 + lr) * N + col0 + wc * 64 + fr * 4) = pk;
    }
  }
}

// ---------------- requant: per-chunk h_q -> per-row h_q' + srow ----------------
__global__ void requant_kernel(const uint4* __restrict__ hq, uint4* __restrict__ hq2,
                               const float* __restrict__ stab, float* __restrict__ srow,
                               int Mrows) {
  const int row = blockIdx.x * 4 + (threadIdx.x >> 6);
  if (row >= Mrows) return;
  const int lane = threadIdx.x & 63;
  const float* st = stab + (size_t)row * 24;
  float sr = 0.f;
#pragma unroll
  for (int i = 0; i < 24; ++i) sr = fmaxf(sr, st[i]);
  if (lane == 0) srow[row] = sr;
  const float rinv = sr > 0.f ? 1.f / sr : 0.f;
  const uint4* in = hq + (size_t)row * 192;
  uint4* outp = hq2 + (size_t)row * 192;
#pragma unroll
  for (int it = 0; it < 3; ++it) {
    const int j = lane + it * 64;
    const float ratio = st[j >> 3] * rinv;
    uint4 iv = in[j], ov;
    unsigned* ip = (unsigned*)&iv;
    unsigned* op = (unsigned*)&ov;
#pragma unroll
    for (int w = 0; w < 4; ++w) {
      unsigned rr = 0;
#pragma unroll
      for (int k = 0; k < 4; ++k) {
        int q = (int)(signed char)((ip[w] >> (k * 8)) & 0xFF);
        int nq = (int)rintf((float)q * ratio);
        rr |= ((unsigned)nq & 0xFF) << (k * 8);
      }
      op[w] = rr;
    }
    outp[j] = ov;
  }
}

// ---------------- fc2: 128x128 pure int8 GEMM (proven loop, unchanged) ----------------
__global__ __launch_bounds__(256) void gemm_fc2(
    const char* __restrict__ A, const char* __restrict__ Bt,
    const float* __restrict__ bias, const float* __restrict__ srow,
    float* __restrict__ Cout, int M, int N, int Kb)
{
  __shared__ char lds[2 * 32768];
  const int tid = threadIdx.x;
  const int lane = tid & 63;
  const int wave = tid >> 6;
  const int wr = wave >> 1;
  const int wc = wave & 1;

  const int nbx = M / 128;
  const int nby = N / 128;
  const int nwg = nbx * nby;
  const int q8 = nwg >> 3, r8 = nwg & 7;
  const int xcd = blockIdx.x & 7, bidx = blockIdx.x >> 3;
  const int wg = (xcd < r8 ? xcd * (q8 + 1) : r8 * (q8 + 1) + (xcd - r8) * q8) + bidx;
  const int r = wg / nby;
  const int c = wg % nby;
  const int row0 = r * 128;
  const int col0 = c * 128;

  const int srw = tid >> 3;
  const int chunk = (tid & 7) ^ (srw & 7);
  const char* Ag = A + (size_t)(row0 + srw) * Kb + chunk * 16;
  const char* Bg = Bt + (size_t)(col0 + srw) * Kb + chunk * 16;
  const int stA = wave * 1024;
  const int stB = 16384 + wave * 1024;

  auto stage = [&](int slot, int h) {
    const int hb = h << 7;
    char* da = lds + slot * 32768 + stA;
    char* db = lds + slot * 32768 + stB;
#pragma unroll
    for (int i = 0; i < 4; ++i)
      stage16(Ag + hb + (size_t)(i * 32) * Kb, da + i * 4096);
#pragma unroll
    for (int i = 0; i < 4; ++i)
      stage16(Bg + hb + (size_t)(i * 32) * Kb, db + i * 4096);
  };

  i32x4 acc[4][4];
#pragma unroll
  for (int i = 0; i < 4; ++i)
#pragma unroll
    for (int j = 0; j < 4; ++j) acc[i][j] = (i32x4)(0);

  const int nS = Kb >> 7;              // 24
  stage(0, 0);
  stage(1, 1);
  asm volatile("s_waitcnt vmcnt(8)" ::: "memory");
  __builtin_amdgcn_s_barrier();

  const int fr = lane & 15;
  const int fg = lane >> 4;
  const int xw = (fg ^ (fr & 7)) << 4;
  const int aoff = (wr * 64 + fr) * 128 + xw;
  const int boff = 16384 + (wc * 64 + fr) * 128 + xw;

  for (int t = 0; t < nS; ++t) {
    const int so = (t & 1) * 32768;
    i32x4 af[2][4], bf[2][4];
#pragma unroll
    for (int h = 0; h < 2; ++h) {
      const int hx = h << 6;
#pragma unroll
      for (int mi = 0; mi < 4; ++mi)
        af[h][mi] = *(const i32x4*)(lds + so + ((aoff ^ hx) + mi * 2048));
#pragma unroll
      for (int ni = 0; ni < 4; ++ni)
        bf[h][ni] = *(const i32x4*)(lds + so + ((boff ^ hx) + ni * 2048));
    }
    asm volatile("s_waitcnt lgkmcnt(0)" ::: "memory");
    __builtin_amdgcn_sched_barrier(0);
    __builtin_amdgcn_s_barrier();
    if (t + 2 < nS) stage(t & 1, t + 2);
    __builtin_amdgcn_s_setprio(1);
#pragma unroll
    for (int h = 0; h < 2; ++h)
#pragma unroll
      for (int mi = 0; mi < 4; ++mi)
#pragma unroll
        for (int ni = 0; ni < 4; ++ni)
          acc[mi][ni] = __builtin_amdgcn_mfma_i32_16x16x64_i8(
              af[h][mi], bf[h][ni], acc[mi][ni], 0, 0, 0);
    __builtin_amdgcn_s_setprio(0);
    if (t + 2 < nS) asm volatile("s_waitcnt vmcnt(8)" ::: "memory");
    else            asm volatile("s_waitcnt vmcnt(0)" ::: "memory");
    __builtin_amdgcn_s_barrier();
  }

  const int orow = row0 + wr * 64 + fg * 4;
  const int ocol = col0 + wc * 64 + fr;
#pragma unroll
  for (int mi = 0; mi < 4; ++mi) {
    float sr[4];
#pragma unroll
    for (int rg = 0; rg < 4; ++rg) sr[rg] = srow[orow + mi * 16 + rg];
#pragma unroll
    for (int ni = 0; ni < 4; ++ni) {
      const int col = ocol + ni * 16;
      const float bv = bias[col];
#pragma unroll
      for (int rg = 0; rg < 4; ++rg) {
        float v = sr[rg] * (float)acc[mi][ni][rg] + bv;
        Cout[(size_t)(orow + mi * 16 + rg) * N + col] = fmaxf(v, 0.f);
      }
    }
  }
}

// ---------------- launch ----------------

extern "C" void kernel_launch(void* const* d_in, const int* in_sizes, int n_in,
                              void* d_out, int out_size, void* d_ws, size_t ws_size,
                              hipStream_t stream) {
  const float* x  = (const float*)d_in[0];
  const float* w1 = (const float*)d_in[1];
  const float* b1 = (const float*)d_in[2];
  const float* w2 = (const float*)d_in[3];
  const float* b2 = (const float*)d_in[4];
  const float* as = (const float*)d_in[5];

  const int Mrows = 64 * 196;   // 12544
  const int D = 768, H = 3072;

  char* ws = (char*)d_ws;
  size_t off = 0;
  auto align256 = [](size_t v) { return (v + 255) & ~(size_t)255; };
  unsigned* mx = (unsigned*)(ws + off); off += 256;
  char* xq8    = (char*)(ws + off);     off += align256((size_t)Mrows * D);
  char* w1q8   = (char*)(ws + off);     off += align256((size_t)H * D);
  char* w2q8   = (char*)(ws + off);     off += align256((size_t)D * H);
  float* b1i = (float*)(ws + off); off += align256((size_t)H * 4);
  float* b2i = (float*)(ws + off); off += align256((size_t)D * 4);
  float* stab = (float*)(ws + off); off += align256((size_t)Mrows * 24 * 4);
  float* srow = (float*)(ws + off); off += align256((size_t)Mrows * 4);
  unsigned char* hq  = (unsigned char*)(ws + off); off += align256((size_t)Mrows * H);
  unsigned char* hq2 = (unsigned char*)(ws + off); off += align256((size_t)Mrows * H);
  if (off > ws_size) return;

  float* out = (float*)d_out;
  float* s_out = out + (out_size - 1);

  hipMemsetAsync(mx, 0, 8, stream);

  const int nw4 = H * D / 4;
  prep_kernel<<<dim3(96, 2), dim3(256), 0, stream>>>(
      (const float4*)w1, (const float4*)w2, nw4, mx);
  quantwb_kernel<<<dim3(1024, 4), dim3(256), 0, stream>>>(
      w1, w2, (unsigned char*)w1q8, (unsigned*)w2q8,
      (const float4*)x, (uchar4*)xq8, Mrows * D / 4,
      b1, b2, b1i, b2i, mx, as, s_out, nw4, H, D);

  // fc1: int8 128x128 single-buffer, 2352 blocks, 5 blocks/CU, Kb = 768
  gemm_fc1<<<dim3((Mrows / 128) * (H / 128)), dim3(256), 0, stream>>>(
      xq8, w1q8, b1i, hq, stab, Mrows, H, D);
  // requant: per-chunk -> per-row scales, 4 rows/block
  requant_kernel<<<dim3(Mrows / 4), dim3(256), 0, stream>>>(
      (const uint4*)hq, (uint4*)hq2, stab, srow, Mrows);
  // fc2: pure int8 128x128, 588 blocks, Kb = 3072
  gemm_fc2<<<dim3((Mrows / 128) * (D / 128)), dim3(256), 0, stream>>>(
      (const char*)hq2, w2q8, b2i, srow, out, Mrows, D, H);
}